// Round 11
// baseline (219.224 us; speedup 1.0000x reference)
//
#include <hip/hip_runtime.h>
#include <hip/hip_bf16.h>
#include <cmath>

#define S_LEN 2048
#define D_MODEL 2048
#define N_HEADS 16
#define Q_LORA 1536
#define KV_LORA 512
#define NOPE 128
#define ROPE_D 64
#define VD 128
#define QHD 192
#define AC_W 2112  // fused a-proj output width: 1536 q_a + 576 ckv

typedef __attribute__((ext_vector_type(8))) short bf16x8;
typedef __attribute__((ext_vector_type(4))) float f32x4;
typedef __attribute__((ext_vector_type(4))) unsigned short u16x4;

static __device__ __forceinline__ unsigned short f2u(float x) {
  union { float f; unsigned u; } v; v.f = x;
  unsigned r = v.u + 0x7fffu + ((v.u >> 16) & 1u);  // RNE
  return (unsigned short)(r >> 16);
}
static __device__ __forceinline__ unsigned short f2u_fast(float x) {  // round-half-up, x>=0
  union { float f; unsigned u; } v; v.f = x;
  return (unsigned short)((v.u + 0x8000u) >> 16);
}
static __device__ __forceinline__ float u2f(unsigned short x) {
  union { unsigned u; float f; } v; v.u = ((unsigned)x) << 16;
  return v.f;
}

#define AS1 __attribute__((address_space(1)))
#define AS3 __attribute__((address_space(3)))
static __device__ __forceinline__ void gload_lds16(const unsigned short* g, unsigned short* l) {
  __builtin_amdgcn_global_load_lds((const AS1 unsigned int*)g, (AS3 unsigned int*)l, 16, 0, 0);
}

// ---------------------------------------------------------------------------
// f32 -> bf16 convert (optionally scaled). n4 = elements/4.
// ---------------------------------------------------------------------------
__global__ __launch_bounds__(256) void conv_bf16(const float* __restrict__ src,
                                                 unsigned short* __restrict__ dst,
                                                 int n4, float scale) {
  for (int i = blockIdx.x * 256 + threadIdx.x; i < n4; i += gridDim.x * 256) {
    const float4 v = ((const float4*)src)[i];
    u16x4 o;
    o[0] = f2u(v.x * scale); o[1] = f2u(v.y * scale);
    o[2] = f2u(v.z * scale); o[3] = f2u(v.w * scale);
    ((u16x4*)dst)[i] = o;
  }
}

// two-segment variant (fused q_a_w + kv_a_w conversion)
__global__ __launch_bounds__(256) void conv2_bf16(const float* __restrict__ srcA, int n4a,
                                                  const float* __restrict__ srcB, int n4total,
                                                  unsigned short* __restrict__ dst) {
  for (int i = blockIdx.x * 256 + threadIdx.x; i < n4total; i += gridDim.x * 256) {
    const float4 v = (i < n4a) ? ((const float4*)srcA)[i] : ((const float4*)srcB)[i - n4a];
    u16x4 o;
    o[0] = f2u(v.x); o[1] = f2u(v.y); o[2] = f2u(v.z); o[3] = f2u(v.w);
    ((u16x4*)dst)[i] = o;
  }
}

// ---------------------------------------------------------------------------
// bf16 MFMA GEMM: C[M,N] = A[M,K] @ W[N,K]^T. 128x64 tile, BK=64, 4 waves
// (each 64x32 output), double-buffered LDS (48 KB), one barrier per 64-k
// step, XOR-swizzled (pre-swizzled global source + same XOR on ds_read).
// (unchanged from round 9)
// ---------------------------------------------------------------------------
template <int MODE>
__global__ __launch_bounds__(256) void gemm_mfma(const unsigned short* __restrict__ A,
                                                 const unsigned short* __restrict__ W,
                                                 void* __restrict__ Cv,
                                                 unsigned short* __restrict__ C2,
                                                 int N, int K) {
  __shared__ unsigned short As[2][8192];  // 128 x 64 bf16
  __shared__ unsigned short Ws[2][4096];  //  64 x 64 bf16
  const int tid = threadIdx.x;
  const int wave = tid >> 6, lane = tid & 63;
  const int col16 = lane & 15, g = lane >> 4;
  const int arow = blockIdx.y * 128, wrow = blockIdx.x * 64;
  const int wm = (wave >> 1) * 64, wn = (wave & 1) * 32;

  const unsigned short* gA[4];
  const unsigned short* gW[2];
  int dA[4], dW[2];
#pragma unroll
  for (int i = 0; i < 4; ++i) {
    const int c = i * 256 + tid;
    const int r = c >> 3, sl = c & 7;
    gA[i] = A + (size_t)(arow + r) * K + (sl ^ (r & 7)) * 8;
    dA[i] = c * 8;
  }
#pragma unroll
  for (int i = 0; i < 2; ++i) {
    const int c = i * 256 + tid;
    const int r = c >> 3, sl = c & 7;
    gW[i] = W + (size_t)(wrow + r) * K + (sl ^ (r & 7)) * 8;
    dW[i] = c * 8;
  }

  f32x4 acc[4][2];
#pragma unroll
  for (int i = 0; i < 4; ++i)
#pragma unroll
    for (int j = 0; j < 2; ++j) acc[i][j] = (f32x4){0.f, 0.f, 0.f, 0.f};

#pragma unroll
  for (int i = 0; i < 4; ++i) gload_lds16(gA[i], &As[0][dA[i]]);
#pragma unroll
  for (int i = 0; i < 2; ++i) gload_lds16(gW[i], &Ws[0][dW[i]]);

  int cur = 0;
  for (int k0 = 0; k0 < K; k0 += 64) {
    __syncthreads();
    if (k0 + 64 < K) {
      const int b = cur ^ 1, kk = k0 + 64;
#pragma unroll
      for (int i = 0; i < 4; ++i) gload_lds16(gA[i] + kk, &As[b][dA[i]]);
#pragma unroll
      for (int i = 0; i < 2; ++i) gload_lds16(gW[i] + kk, &Ws[b][dW[i]]);
    }
#pragma unroll
    for (int kh = 0; kh < 2; ++kh) {
      bf16x8 af[4], bfr[2];
#pragma unroll
      for (int i = 0; i < 4; ++i) {
        const int row = wm + i * 16 + col16;
        af[i] = *(const bf16x8*)(&As[cur][row * 64 + (((kh * 4 + g) ^ (row & 7)) * 8)]);
      }
#pragma unroll
      for (int j = 0; j < 2; ++j) {
        const int row = wn + j * 16 + col16;
        bfr[j] = *(const bf16x8*)(&Ws[cur][row * 64 + (((kh * 4 + g) ^ (row & 7)) * 8)]);
      }
#pragma unroll
      for (int i = 0; i < 4; ++i)
#pragma unroll
        for (int j = 0; j < 2; ++j)
          acc[i][j] = __builtin_amdgcn_mfma_f32_16x16x32_bf16(af[i], bfr[j], acc[i][j], 0, 0, 0);
    }
    cur ^= 1;
  }

#pragma unroll
  for (int i = 0; i < 4; ++i)
#pragma unroll
    for (int j = 0; j < 2; ++j) {
      const int col = wrow + wn + j * 16 + col16;
      const int row0 = arow + wm + i * 16 + g * 4;
#pragma unroll
      for (int r = 0; r < 4; ++r) {
        if constexpr (MODE == 0)
          ((float*)Cv)[(size_t)(row0 + r) * N + col] = acc[i][j][r];
        else if constexpr (MODE == 1)
          ((unsigned short*)Cv)[(size_t)(row0 + r) * N + col] = f2u(acc[i][j][r]);
        else {
          const int hh = col >> 8, d = col & 255;
          if (d < NOPE)
            C2[((size_t)hh * S_LEN + row0 + r) * QHD + d] = f2u(acc[i][j][r]);
          else
            ((unsigned short*)Cv)[(size_t)(row0 + r) * (N_HEADS * 256) + col] = f2u(acc[i][j][r]);
        }
      }
    }
}

// ---------------------------------------------------------------------------
// RMSNorm over last dim, f32 in -> bf16 out.
// ---------------------------------------------------------------------------
__global__ __launch_bounds__(256) void rmsnorm_kernel(const float* __restrict__ src, int src_ld,
                                                      const float* __restrict__ w,
                                                      unsigned short* __restrict__ dst, int dst_ld,
                                                      int dim) {
  const int row = blockIdx.x;
  const float* x = src + (size_t)row * src_ld;
  float ss = 0.f;
  for (int i = threadIdx.x; i < dim; i += 256) {
    float v = x[i];
    ss += v * v;
  }
#pragma unroll
  for (int off = 32; off; off >>= 1) ss += __shfl_xor(ss, off);
  __shared__ float red[4];
  const int wv = threadIdx.x >> 6, ln = threadIdx.x & 63;
  if (ln == 0) red[wv] = ss;
  __syncthreads();
  const float tot = red[0] + red[1] + red[2] + red[3];
  const float scale = rsqrtf(tot / (float)dim + 1e-6f);
  for (int i = threadIdx.x; i < dim; i += 256) {
    dst[(size_t)row * dst_ld + i] = f2u(w[i] * (x[i] * scale));
  }
}

// ---------------------------------------------------------------------------
// RoPE: q_pe slices of bf16 qbuf in place; k_pe -> broadcast into Kb.
// ---------------------------------------------------------------------------
__global__ void rope_kernel(unsigned short* __restrict__ q, const float* __restrict__ ac,
                            unsigned short* __restrict__ Kb, const int* __restrict__ pos_ids) {
  const int s = blockIdx.x;
  const int j = threadIdx.x;  // 0..31
  const float t = (float)pos_ids[s];
  const float invf = powf(50000.0f, -(float)(2 * j) / 64.0f);
  const float ang = t * invf;
  const float c = cosf(ang), sn = sinf(ang);
  for (int h = 0; h < N_HEADS; ++h) {
    unsigned short* base = q + (size_t)s * (N_HEADS * QHD) + h * QHD + NOPE;
    const float x0 = u2f(base[2 * j]), x1 = u2f(base[2 * j + 1]);
    __syncthreads();
    base[j] = f2u(x0 * c - x1 * sn);
    base[32 + j] = f2u(x1 * c + x0 * sn);
    __syncthreads();
  }
  const float* kb = ac + (size_t)s * AC_W + 2048;
  const unsigned short r0 = f2u(kb[2 * j] * c - kb[2 * j + 1] * sn);
  const unsigned short r1 = f2u(kb[2 * j + 1] * c + kb[2 * j] * sn);
#pragma unroll
  for (int h = 0; h < N_HEADS; ++h) {
    unsigned short* kd = Kb + ((size_t)h * S_LEN + s) * QHD + NOPE;
    kd[j] = r0;
    kd[32 + j] = r1;
  }
}

// ---------------------------------------------------------------------------
// V transpose + PERMUTED column order (16x16 PV fragment order, as R5-R9):
// source column k stored at p = ((k&15)>>2)*8 + ((k>>4)&1)*4 + (k&3).
// ---------------------------------------------------------------------------
__global__ __launch_bounds__(256) void build_vt(const unsigned short* __restrict__ kv,
                                                unsigned short* __restrict__ Vt) {
  __shared__ unsigned short t[32][33];
  const int s0 = blockIdx.x * 32, d0 = blockIdx.y * 32, h = blockIdx.z;
  const int tx = threadIdx.x & 31, ty = threadIdx.x >> 5;
#pragma unroll
  for (int i = 0; i < 4; ++i) {
    const int s = s0 + ty + i * 8;
    t[ty + i * 8][tx] = kv[(size_t)s * (N_HEADS * 256) + h * 256 + NOPE + d0 + tx];
  }
  __syncthreads();
  const int p = ((tx & 15) >> 2) * 8 + ((tx >> 4) & 1) * 4 + (tx & 3);
#pragma unroll
  for (int i = 0; i < 4; ++i) {
    const int d = d0 + ty + i * 8;
    Vt[((size_t)h * VD + d) * S_LEN + s0 + p] = t[tx][ty + i * 8];
  }
}

// ---------------------------------------------------------------------------
// Split-4 MFMA flash attention, 32 q-cols per wave at R9 occupancy.
// Block = 256 thr = 4 waves x 32 q = 128 rows; KVBLK=32 double-buffered
// (40 KB -> 2 blocks/CU, 8 waves/CU, same as R9); split s takes tiles
// j == s (mod 4) -> exactly t+1 tiles (perfect causal balance); grid 1024.
// Each K/V ds_read_b128 feeds TWO MFMAs (q-groups A/B) -> LDS bytes/FLOP
// halved vs R9 (kernel was 87% LDS-BW-bound), per-CU intervals ~17 vs 34.
// bf16 partials + (m,l); combine4 merges. exp2 softmax, defer-max THR=8,
// diagonal-only masking, XCD head-pair, balanced t-map (CU quad sums 34).
// ---------------------------------------------------------------------------
__global__ __launch_bounds__(256) void flash_attn(const unsigned short* __restrict__ Q,   // (S,3072) pre-scaled
                                                  const unsigned short* __restrict__ Kb,  // (H,S,192)
                                                  const unsigned short* __restrict__ Vt,  // (H,128,S) permuted
                                                  unsigned short* __restrict__ Pb,        // (S,4,16,128) bf16 partials
                                                  float2* __restrict__ mlb) {             // (S,4,16) {m,l}
  __shared__ unsigned short Ks[2][32 * QHD];   // 2 x 12 KB
  __shared__ unsigned short Vs[2][VD * 32];    // 2 x  8 KB
  const int tid = threadIdx.x;
  const int wave = tid >> 6, lane = tid & 63;
  const int g = lane >> 4, col = lane & 15;
  const int lin = (int)blockIdx.x;                    // 0..1023
  const int h = ((lin & 7) << 1) | ((lin >> 3) & 1);  // XCD owns a head pair
  const int s = (lin >> 4) & 3;                       // k-split
  const int z = lin >> 6;                             // 0..15
  const int zj = z >> 2, za = z & 3;
  const int t = 4 * zj + ((zj + za) & 3);             // bijective; CU quad sums 30 (+4)
  const int qwv = t * 128 + wave * 32;
  const int qrA = qwv + col, qrB = qwv + 16 + col;

  bf16x8 qfA[6], qfB[6];
  {
    const unsigned short* qa = Q + (size_t)qrA * (N_HEADS * QHD) + h * QHD + g * 8;
    const unsigned short* qb = Q + (size_t)qrB * (N_HEADS * QHD) + h * QHD + g * 8;
#pragma unroll
    for (int i = 0; i < 6; ++i) {
      qfA[i] = *(const bf16x8*)(qa + i * 32);
      qfB[i] = *(const bf16x8*)(qb + i * 32);
    }
  }

  const unsigned short* KbH = Kb + (size_t)h * S_LEN * QHD;
  const unsigned short* VtH = Vt + (size_t)h * VD * S_LEN;

  // staging source offsets (pre-swizzled slots; fixed across tiles)
  int eK[3], eV[2];
#pragma unroll
  for (int i = 0; i < 3; ++i) {                 // 768 K chunks of 16B
    const int c = i * 256 + tid;
    const int r = c / 24, sl = c - r * 24;
    eK[i] = r * QHD + (((sl & 24) | ((sl & 7) ^ (r & 7)))) * 8;
  }
#pragma unroll
  for (int i = 0; i < 2; ++i) {                 // 512 V chunks of 16B
    const int c = i * 256 + tid;
    const int d = c >> 2, sl = c & 3;
    eV[i] = d * S_LEN + ((sl ^ (d & 3))) * 8;
  }

  f32x4 oA[8], oB[8];
#pragma unroll
  for (int i = 0; i < 8; ++i) {
    oA[i] = (f32x4){0.f, 0.f, 0.f, 0.f};
    oB[i] = (f32x4){0.f, 0.f, 0.f, 0.f};
  }
  float mA = -1e30f, lA = 0.f, mB = -1e30f, lB = 0.f;

  const int nT = t + 1;  // tiles j = 4*it + s

  // prologue: stage tile j=s into buffer 0
  {
    const unsigned short* kp = KbH + (size_t)s * 32 * QHD;
    const unsigned short* vp = VtH + s * 32;
#pragma unroll
    for (int i = 0; i < 3; ++i) gload_lds16(kp + eK[i], &Ks[0][(i * 256 + tid) * 8]);
#pragma unroll
    for (int i = 0; i < 2; ++i) gload_lds16(vp + eV[i], &Vs[0][(i * 256 + tid) * 8]);
  }

  int xK[6];
#pragma unroll
  for (int i = 0; i < 6; ++i) xK[i] = ((4 * i + g) ^ (col & 7)) * 8;
  const int rbK = col * QHD;
  const int xV = (g ^ (col & 3)) * 8;
  const int rbV = col * 32;

  for (int it = 0; it < nT; ++it) {
    __syncthreads();
    if (it + 1 < nT) {
      const int jn = 4 * (it + 1) + s;
      const unsigned short* kp = KbH + (size_t)jn * 32 * QHD;
      const unsigned short* vp = VtH + jn * 32;
      const int b = (it + 1) & 1;
#pragma unroll
      for (int i = 0; i < 3; ++i) gload_lds16(kp + eK[i], &Ks[b][(i * 256 + tid) * 8]);
#pragma unroll
      for (int i = 0; i < 2; ++i) gload_lds16(vp + eV[i], &Vs[b][(i * 256 + tid) * 8]);
    }
    const int k0 = 32 * (4 * it + s);
    if (k0 <= qwv + 31) {   // wave may idle on its last split tile
      const unsigned short* Ksc = Ks[it & 1];
      const unsigned short* Vsc = Vs[it & 1];

      f32x4 cA0 = (f32x4){0.f, 0.f, 0.f, 0.f}, cA1 = cA0, cB0 = cA0, cB1 = cA0;
      __builtin_amdgcn_s_setprio(1);
#pragma unroll
      for (int dt = 0; dt < 6; ++dt) {
        const bf16x8 a0 = *(const bf16x8*)(Ksc + rbK + xK[dt]);
        const bf16x8 a1 = *(const bf16x8*)(Ksc + rbK + 16 * QHD + xK[dt]);
        cA0 = __builtin_amdgcn_mfma_f32_16x16x32_bf16(a0, qfA[dt], cA0, 0, 0, 0);
        cA1 = __builtin_amdgcn_mfma_f32_16x16x32_bf16(a1, qfA[dt], cA1, 0, 0, 0);
        cB0 = __builtin_amdgcn_mfma_f32_16x16x32_bf16(a0, qfB[dt], cB0, 0, 0, 0);
        cB1 = __builtin_amdgcn_mfma_f32_16x16x32_bf16(a1, qfB[dt], cB1, 0, 0, 0);
      }
      __builtin_amdgcn_s_setprio(0);

      // causal mask only on diagonal-overlapping tiles (k = k0 + 16f + 4g + r)
      if (k0 + 31 > qwv) {
#pragma unroll
        for (int r = 0; r < 4; ++r) {
          const int kk = k0 + 4 * g + r;
          if (kk > qrA) cA0[r] = -1e30f;
          if (kk + 16 > qrA) cA1[r] = -1e30f;
          if (kk > qrB) cB0[r] = -1e30f;
          if (kk + 16 > qrB) cB1[r] = -1e30f;
        }
      }
      // softmax A
      bf16x8 pbA, pbB;
      {
        float bm = fmaxf(fmaxf(fmaxf(cA0[0], cA0[1]), fmaxf(cA0[2], cA0[3])),
                         fmaxf(fmaxf(cA1[0], cA1[1]), fmaxf(cA1[2], cA1[3])));
        bm = fmaxf(bm, __shfl_xor(bm, 16));
        bm = fmaxf(bm, __shfl_xor(bm, 32));
        const bool skip = __all(bm <= mA + 8.f);
        const float mn = skip ? mA : fmaxf(mA, bm);
        float ps = 0.f;
#pragma unroll
        for (int r = 0; r < 4; ++r) {
          const float p0 = exp2f(cA0[r] - mn);
          const float p1 = exp2f(cA1[r] - mn);
          ps += p0 + p1;
          pbA[r] = (short)f2u_fast(p0);
          pbA[4 + r] = (short)f2u_fast(p1);
        }
        ps += __shfl_xor(ps, 16);
        ps += __shfl_xor(ps, 32);
        if (skip) {
          lA += ps;
        } else {
          const float corr = exp2f(mA - mn);
          lA = lA * corr + ps;
          mA = mn;
#pragma unroll
          for (int i = 0; i < 8; ++i) {
            oA[i][0] *= corr; oA[i][1] *= corr; oA[i][2] *= corr; oA[i][3] *= corr;
          }
        }
      }
      // softmax B
      {
        float bm = fmaxf(fmaxf(fmaxf(cB0[0], cB0[1]), fmaxf(cB0[2], cB0[3])),
                         fmaxf(fmaxf(cB1[0], cB1[1]), fmaxf(cB1[2], cB1[3])));
        bm = fmaxf(bm, __shfl_xor(bm, 16));
        bm = fmaxf(bm, __shfl_xor(bm, 32));
        const bool skip = __all(bm <= mB + 8.f);
        const float mn = skip ? mB : fmaxf(mB, bm);
        float ps = 0.f;
#pragma unroll
        for (int r = 0; r < 4; ++r) {
          const float p0 = exp2f(cB0[r] - mn);
          const float p1 = exp2f(cB1[r] - mn);
          ps += p0 + p1;
          pbB[r] = (short)f2u_fast(p0);
          pbB[4 + r] = (short)f2u_fast(p1);
        }
        ps += __shfl_xor(ps, 16);
        ps += __shfl_xor(ps, 32);
        if (skip) {
          lB += ps;
        } else {
          const float corr = exp2f(mB - mn);
          lB = lB * corr + ps;
          mB = mn;
#pragma unroll
          for (int i = 0; i < 8; ++i) {
            oB[i][0] *= corr; oB[i][1] *= corr; oB[i][2] *= corr; oB[i][3] *= corr;
          }
        }
      }
      // PV: each V read feeds TWO MFMAs (groups A and B)
      __builtin_amdgcn_s_setprio(1);
#pragma unroll
      for (int db = 0; db < 8; ++db) {
        const bf16x8 va = *(const bf16x8*)(Vsc + db * 512 + rbV + xV);
        oA[db] = __builtin_amdgcn_mfma_f32_16x16x32_bf16(va, pbA, oA[db], 0, 0, 0);
        oB[db] = __builtin_amdgcn_mfma_f32_16x16x32_bf16(va, pbB, oB[db], 0, 0, 0);
      }
      __builtin_amdgcn_s_setprio(0);
    }
  }

  // epilogue: bf16 partials (d = db*16 + 4g + r) + (m,l) for both q-groups
  unsigned short* prA = Pb + (((size_t)qrA * 4 + s) * N_HEADS + h) * VD;
  unsigned short* prB = Pb + (((size_t)qrB * 4 + s) * N_HEADS + h) * VD;
#pragma unroll
  for (int db = 0; db < 8; ++db) {
    u16x4 wa, wb;
#pragma unroll
    for (int r = 0; r < 4; ++r) {
      wa[r] = f2u(oA[db][r]);
      wb[r] = f2u(oB[db][r]);
    }
    *(uint2*)(prA + db * 16 + 4 * g) = __builtin_bit_cast(uint2, wa);
    *(uint2*)(prB + db * 16 + 4 * g) = __builtin_bit_cast(uint2, wb);
  }
  if (g == 0) {
    mlb[((size_t)qrA * 4 + s) * N_HEADS + h] = make_float2(mA, lA);
    mlb[((size_t)qrB * 4 + s) * N_HEADS + h] = make_float2(mB, lB);
  }
}

// ---------------------------------------------------------------------------
// Merge the 4 k-splits: out = sum_s w_s*O_s / sum_s w_s*l_s, bf16.
// ---------------------------------------------------------------------------
__global__ __launch_bounds__(256) void combine4(const unsigned short* __restrict__ Pb,
                                                const float2* __restrict__ mlb,
                                                unsigned short* __restrict__ outb) {
  const int idx = blockIdx.x * 256 + threadIdx.x;  // exactly 524288
  const int d8 = idx & 15, hq = idx >> 4;
  const int h = hq & 15, q = hq >> 4;
  float2 ml[4];
  float M = -1e30f;
#pragma unroll
  for (int s = 0; s < 4; ++s) {
    ml[s] = mlb[((size_t)q * 4 + s) * N_HEADS + h];
    M = fmaxf(M, ml[s].x);
  }
  float w[4], den = 0.f;
#pragma unroll
  for (int s = 0; s < 4; ++s) {
    w[s] = exp2f(ml[s].x - M);
    den += w[s] * ml[s].y;
  }
  const float inv = 1.f / den;
  float acc[8] = {};
#pragma unroll
  for (int s = 0; s < 4; ++s) {
    const bf16x8 v = *(const bf16x8*)(Pb + (((size_t)q * 4 + s) * N_HEADS + h) * VD + d8 * 8);
    const float ws = w[s] * inv;
#pragma unroll
    for (int e = 0; e < 8; ++e) acc[e] += u2f((unsigned short)v[e]) * ws;
  }
  u16x4 o0, o1;
#pragma unroll
  for (int e = 0; e < 4; ++e) { o0[e] = f2u(acc[e]); o1[e] = f2u(acc[4 + e]); }
  unsigned short* dst = outb + ((size_t)q * N_HEADS + h) * VD + d8 * 8;
  *(uint2*)(dst) = __builtin_bit_cast(uint2, o0);
  *(uint2*)(dst + 4) = __builtin_bit_cast(uint2, o1);
}

// ---------------------------------------------------------------------------
extern "C" void kernel_launch(void* const* d_in, const int* in_sizes, int n_in,
                              void* d_out, int out_size, void* d_ws, size_t ws_size,
                              hipStream_t stream) {
  const float* hidden    = (const float*)d_in[0];
  const int*   pos       = (const int*)d_in[1];
  const float* q_a_w     = (const float*)d_in[2];
  const float* q_a_ln_w  = (const float*)d_in[3];
  const float* q_b_w     = (const float*)d_in[4];
  const float* kv_a_w    = (const float*)d_in[5];
  const float* kv_a_ln_w = (const float*)d_in[6];
  const float* kv_b_w    = (const float*)d_in[7];
  const float* o_w       = (const float*)d_in[8];
  float* out = (float*)d_out;
  (void)in_sizes; (void)n_in; (void)out_size; (void)ws_size;

  // workspace layout (bytes); total ~94 MB
  char* base = (char*)d_ws;
  unsigned short* qbuf  = (unsigned short*)(base);              // S*3072 bf16  12.58MB
  unsigned short* kvbuf = (unsigned short*)(base + 12582912);   // S*4096 bf16  (V half)
  unsigned short* Pbuf  = (unsigned short*)(base + 12582912);   //   overlay: S*4*2048 bf16 = 33.55MB
  float2*         mlb   = (float2*)(base + 46137344);           //   overlay: S*4*16 float2 = 1MB (qan dead)
  float*          ac    = (float*)(base + 29360128);            // S*2112 f32   17.30MB
  unsigned short* qan   = (unsigned short*)(base + 46661632);   // S*1536 bf16   6.29MB
  unsigned short* ckvn  = (unsigned short*)(base + 52953088);   // S*512 bf16    2.10MB
  unsigned short* Hb    = (unsigned short*)(base + 55050240);   // S*2048 bf16   8.39MB
  unsigned short* Vt    = (unsigned short*)(base + 55050240);   //   overlay (Hb dead after a-proj)
  unsigned short* wbuf  = (unsigned short*)(base + 63438848);   // 4.72M bf16    9.44MB
  unsigned short* attnb = (unsigned short*)(base + 72876032);   // S*2048 bf16   8.39MB
  unsigned short* Kb    = (unsigned short*)(base + 81264640);   // 16*S*192 bf16 12.58MB

  const dim3 b256(256);
  // 192^-0.5 * log2(e): scores come out of QK^T directly in log2 domain
  const float qscale = 0.07216878364870323f * 1.4426950408889634f;

  conv_bf16<<<2048, b256, 0, stream>>>(hidden, Hb, (S_LEN * D_MODEL) / 4, 1.f);

  // fused a-proj: W = [q_a_w ; kv_a_w] (2112 x 2048), C = ac f32 (S x 2112)
  conv2_bf16<<<2048, b256, 0, stream>>>(q_a_w, (Q_LORA * D_MODEL) / 4,
                                        kv_a_w, (AC_W * D_MODEL) / 4, wbuf);
  gemm_mfma<0><<<dim3(AC_W / 64, S_LEN / 128), b256, 0, stream>>>(Hb, wbuf, ac, nullptr, AC_W, D_MODEL);

  rmsnorm_kernel<<<S_LEN, b256, 0, stream>>>(ac, AC_W, q_a_ln_w, qan, Q_LORA, Q_LORA);
  rmsnorm_kernel<<<S_LEN, b256, 0, stream>>>(ac + Q_LORA, AC_W, kv_a_ln_w, ckvn, KV_LORA, KV_LORA);

  // qbuf = qan @ (qscale*q_b_w)^T   (bf16 out)
  conv_bf16<<<2048, b256, 0, stream>>>(q_b_w, wbuf, (N_HEADS * QHD * Q_LORA) / 4, qscale);
  gemm_mfma<1><<<dim3(N_HEADS * QHD / 64, S_LEN / 128), b256, 0, stream>>>(qan, wbuf, qbuf, nullptr, N_HEADS * QHD, Q_LORA);

  // kv_b: k_nope -> Kb directly, values -> kvbuf
  conv_bf16<<<2048, b256, 0, stream>>>(kv_b_w, wbuf, (N_HEADS * 256 * KV_LORA) / 4, 1.f);
  gemm_mfma<2><<<dim3(N_HEADS * 256 / 64, S_LEN / 128), b256, 0, stream>>>(ckvn, wbuf, kvbuf, Kb, N_HEADS * 256, KV_LORA);

  // rope: qbuf q_pe in place; k_pe -> Kb cols 128..192 (all heads)
  rope_kernel<<<S_LEN, 32, 0, stream>>>(qbuf, ac, Kb, pos);

  build_vt<<<dim3(S_LEN / 32, VD / 32, N_HEADS), b256, 0, stream>>>(kvbuf, Vt);

  // split-4 flash (bf16 partials over kvbuf/ac region — dead) + combine
  flash_attn<<<dim3(1024), b256, 0, stream>>>(qbuf, Kb, Vt, Pbuf, mlb);
  combine4<<<2048, b256, 0, stream>>>(Pbuf, mlb, attnb);

  conv_bf16<<<2048, b256, 0, stream>>>(o_w, wbuf, (D_MODEL * N_HEADS * VD) / 4, 1.f);
  gemm_mfma<0><<<dim3(D_MODEL / 64, S_LEN / 128), b256, 0, stream>>>(attnb, wbuf, out, nullptr, D_MODEL, N_HEADS * VD);
}

// Round 12
// 204.664 us; speedup vs baseline: 1.0711x; 1.0711x over previous
//
#include <hip/hip_runtime.h>
#include <hip/hip_bf16.h>
#include <cmath>

#define S_LEN 2048
#define D_MODEL 2048
#define N_HEADS 16
#define Q_LORA 1536
#define KV_LORA 512
#define NOPE 128
#define ROPE_D 64
#define VD 128
#define QHD 192
#define AC_W 2112  // fused a-proj output width: 1536 q_a + 576 ckv

typedef __attribute__((ext_vector_type(8))) short bf16x8;
typedef __attribute__((ext_vector_type(4))) float f32x4;
typedef __attribute__((ext_vector_type(4))) unsigned short u16x4;

static __device__ __forceinline__ unsigned short f2u(float x) {
  union { float f; unsigned u; } v; v.f = x;
  unsigned r = v.u + 0x7fffu + ((v.u >> 16) & 1u);  // RNE
  return (unsigned short)(r >> 16);
}
static __device__ __forceinline__ unsigned short f2u_fast(float x) {  // round-half-up, x>=0
  union { float f; unsigned u; } v; v.f = x;
  return (unsigned short)((v.u + 0x8000u) >> 16);
}
static __device__ __forceinline__ float u2f(unsigned short x) {
  union { unsigned u; float f; } v; v.u = ((unsigned)x) << 16;
  return v.f;
}

#define AS1 __attribute__((address_space(1)))
#define AS3 __attribute__((address_space(3)))
static __device__ __forceinline__ void gload_lds16(const unsigned short* g, unsigned short* l) {
  __builtin_amdgcn_global_load_lds((const AS1 unsigned int*)g, (AS3 unsigned int*)l, 16, 0, 0);
}

// ---------------------------------------------------------------------------
// f32 -> bf16 convert (optionally scaled). n4 = elements/4.
// ---------------------------------------------------------------------------
__global__ __launch_bounds__(256) void conv_bf16(const float* __restrict__ src,
                                                 unsigned short* __restrict__ dst,
                                                 int n4, float scale) {
  for (int i = blockIdx.x * 256 + threadIdx.x; i < n4; i += gridDim.x * 256) {
    const float4 v = ((const float4*)src)[i];
    u16x4 o;
    o[0] = f2u(v.x * scale); o[1] = f2u(v.y * scale);
    o[2] = f2u(v.z * scale); o[3] = f2u(v.w * scale);
    ((u16x4*)dst)[i] = o;
  }
}

// two-segment variant (fused q_a_w + kv_a_w conversion)
__global__ __launch_bounds__(256) void conv2_bf16(const float* __restrict__ srcA, int n4a,
                                                  const float* __restrict__ srcB, int n4total,
                                                  unsigned short* __restrict__ dst) {
  for (int i = blockIdx.x * 256 + threadIdx.x; i < n4total; i += gridDim.x * 256) {
    const float4 v = (i < n4a) ? ((const float4*)srcA)[i] : ((const float4*)srcB)[i - n4a];
    u16x4 o;
    o[0] = f2u(v.x); o[1] = f2u(v.y); o[2] = f2u(v.z); o[3] = f2u(v.w);
    ((u16x4*)dst)[i] = o;
  }
}

// ---------------------------------------------------------------------------
// bf16 MFMA GEMM: C[M,N] = A[M,K] @ W[N,K]^T. 128x64 tile, BK=64, 4 waves
// (each 64x32 output), double-buffered LDS (48 KB), one barrier per 64-k
// step, XOR-swizzled (pre-swizzled global source + same XOR on ds_read).
// (unchanged from round 9)
// ---------------------------------------------------------------------------
template <int MODE>
__global__ __launch_bounds__(256) void gemm_mfma(const unsigned short* __restrict__ A,
                                                 const unsigned short* __restrict__ W,
                                                 void* __restrict__ Cv,
                                                 unsigned short* __restrict__ C2,
                                                 int N, int K) {
  __shared__ unsigned short As[2][8192];  // 128 x 64 bf16
  __shared__ unsigned short Ws[2][4096];  //  64 x 64 bf16
  const int tid = threadIdx.x;
  const int wave = tid >> 6, lane = tid & 63;
  const int col16 = lane & 15, g = lane >> 4;
  const int arow = blockIdx.y * 128, wrow = blockIdx.x * 64;
  const int wm = (wave >> 1) * 64, wn = (wave & 1) * 32;

  const unsigned short* gA[4];
  const unsigned short* gW[2];
  int dA[4], dW[2];
#pragma unroll
  for (int i = 0; i < 4; ++i) {
    const int c = i * 256 + tid;
    const int r = c >> 3, sl = c & 7;
    gA[i] = A + (size_t)(arow + r) * K + (sl ^ (r & 7)) * 8;
    dA[i] = c * 8;
  }
#pragma unroll
  for (int i = 0; i < 2; ++i) {
    const int c = i * 256 + tid;
    const int r = c >> 3, sl = c & 7;
    gW[i] = W + (size_t)(wrow + r) * K + (sl ^ (r & 7)) * 8;
    dW[i] = c * 8;
  }

  f32x4 acc[4][2];
#pragma unroll
  for (int i = 0; i < 4; ++i)
#pragma unroll
    for (int j = 0; j < 2; ++j) acc[i][j] = (f32x4){0.f, 0.f, 0.f, 0.f};

#pragma unroll
  for (int i = 0; i < 4; ++i) gload_lds16(gA[i], &As[0][dA[i]]);
#pragma unroll
  for (int i = 0; i < 2; ++i) gload_lds16(gW[i], &Ws[0][dW[i]]);

  int cur = 0;
  for (int k0 = 0; k0 < K; k0 += 64) {
    __syncthreads();
    if (k0 + 64 < K) {
      const int b = cur ^ 1, kk = k0 + 64;
#pragma unroll
      for (int i = 0; i < 4; ++i) gload_lds16(gA[i] + kk, &As[b][dA[i]]);
#pragma unroll
      for (int i = 0; i < 2; ++i) gload_lds16(gW[i] + kk, &Ws[b][dW[i]]);
    }
#pragma unroll
    for (int kh = 0; kh < 2; ++kh) {
      bf16x8 af[4], bfr[2];
#pragma unroll
      for (int i = 0; i < 4; ++i) {
        const int row = wm + i * 16 + col16;
        af[i] = *(const bf16x8*)(&As[cur][row * 64 + (((kh * 4 + g) ^ (row & 7)) * 8)]);
      }
#pragma unroll
      for (int j = 0; j < 2; ++j) {
        const int row = wn + j * 16 + col16;
        bfr[j] = *(const bf16x8*)(&Ws[cur][row * 64 + (((kh * 4 + g) ^ (row & 7)) * 8)]);
      }
#pragma unroll
      for (int i = 0; i < 4; ++i)
#pragma unroll
        for (int j = 0; j < 2; ++j)
          acc[i][j] = __builtin_amdgcn_mfma_f32_16x16x32_bf16(af[i], bfr[j], acc[i][j], 0, 0, 0);
    }
    cur ^= 1;
  }

#pragma unroll
  for (int i = 0; i < 4; ++i)
#pragma unroll
    for (int j = 0; j < 2; ++j) {
      const int col = wrow + wn + j * 16 + col16;
      const int row0 = arow + wm + i * 16 + g * 4;
#pragma unroll
      for (int r = 0; r < 4; ++r) {
        if constexpr (MODE == 0)
          ((float*)Cv)[(size_t)(row0 + r) * N + col] = acc[i][j][r];
        else if constexpr (MODE == 1)
          ((unsigned short*)Cv)[(size_t)(row0 + r) * N + col] = f2u(acc[i][j][r]);
        else {
          const int hh = col >> 8, d = col & 255;
          if (d < NOPE)
            C2[((size_t)hh * S_LEN + row0 + r) * QHD + d] = f2u(acc[i][j][r]);
          else
            ((unsigned short*)Cv)[(size_t)(row0 + r) * (N_HEADS * 256) + col] = f2u(acc[i][j][r]);
        }
      }
    }
}

// ---------------------------------------------------------------------------
// Fused RMSNorm: blockIdx.y = 0 -> q_a slice (dim 1536), 1 -> kv slice (512).
// f32 in (ac, ld 2112) -> bf16 out.
// ---------------------------------------------------------------------------
__global__ __launch_bounds__(256) void rmsnorm2_kernel(const float* __restrict__ ac,
                                                       const float* __restrict__ wq,
                                                       const float* __restrict__ wkv,
                                                       unsigned short* __restrict__ qan,
                                                       unsigned short* __restrict__ ckvn) {
  const int row = blockIdx.x;
  const bool kv = blockIdx.y != 0;
  const float* x = ac + (size_t)row * AC_W + (kv ? Q_LORA : 0);
  const float* w = kv ? wkv : wq;
  unsigned short* dst = kv ? (ckvn + (size_t)row * KV_LORA) : (qan + (size_t)row * Q_LORA);
  const int dim = kv ? KV_LORA : Q_LORA;
  float ss = 0.f;
  for (int i = threadIdx.x; i < dim; i += 256) {
    float v = x[i];
    ss += v * v;
  }
#pragma unroll
  for (int off = 32; off; off >>= 1) ss += __shfl_xor(ss, off);
  __shared__ float red[4];
  const int wv = threadIdx.x >> 6, ln = threadIdx.x & 63;
  if (ln == 0) red[wv] = ss;
  __syncthreads();
  const float tot = red[0] + red[1] + red[2] + red[3];
  const float scale = rsqrtf(tot / (float)dim + 1e-6f);
  for (int i = threadIdx.x; i < dim; i += 256) {
    dst[i] = f2u(w[i] * (x[i] * scale));
  }
}

// ---------------------------------------------------------------------------
// RoPE: q_pe slices of bf16 qbuf in place; k_pe -> broadcast into Kb.
// ---------------------------------------------------------------------------
__global__ void rope_kernel(unsigned short* __restrict__ q, const float* __restrict__ ac,
                            unsigned short* __restrict__ Kb, const int* __restrict__ pos_ids) {
  const int s = blockIdx.x;
  const int j = threadIdx.x;  // 0..31
  const float t = (float)pos_ids[s];
  const float invf = powf(50000.0f, -(float)(2 * j) / 64.0f);
  const float ang = t * invf;
  const float c = cosf(ang), sn = sinf(ang);
  for (int h = 0; h < N_HEADS; ++h) {
    unsigned short* base = q + (size_t)s * (N_HEADS * QHD) + h * QHD + NOPE;
    const float x0 = u2f(base[2 * j]), x1 = u2f(base[2 * j + 1]);
    __syncthreads();
    base[j] = f2u(x0 * c - x1 * sn);
    base[32 + j] = f2u(x1 * c + x0 * sn);
    __syncthreads();
  }
  const float* kb = ac + (size_t)s * AC_W + 2048;
  const unsigned short r0 = f2u(kb[2 * j] * c - kb[2 * j + 1] * sn);
  const unsigned short r1 = f2u(kb[2 * j + 1] * c + kb[2 * j] * sn);
#pragma unroll
  for (int h = 0; h < N_HEADS; ++h) {
    unsigned short* kd = Kb + ((size_t)h * S_LEN + s) * QHD + NOPE;
    kd[j] = r0;
    kd[32 + j] = r1;
  }
}

// ---------------------------------------------------------------------------
// V transpose + PERMUTED column order (16x16 PV fragment order):
// source column k stored at p = ((k&15)>>2)*8 + ((k>>4)&1)*4 + (k&3).
// ---------------------------------------------------------------------------
__global__ __launch_bounds__(256) void build_vt(const unsigned short* __restrict__ kv,
                                                unsigned short* __restrict__ Vt) {
  __shared__ unsigned short t[32][33];
  const int s0 = blockIdx.x * 32, d0 = blockIdx.y * 32, h = blockIdx.z;
  const int tx = threadIdx.x & 31, ty = threadIdx.x >> 5;
#pragma unroll
  for (int i = 0; i < 4; ++i) {
    const int s = s0 + ty + i * 8;
    t[ty + i * 8][tx] = kv[(size_t)s * (N_HEADS * 256) + h * 256 + NOPE + d0 + tx];
  }
  __syncthreads();
  const int p = ((tx & 15) >> 2) * 8 + ((tx >> 4) & 1) * 4 + (tx & 3);
#pragma unroll
  for (int i = 0; i < 4; ++i) {
    const int d = d0 + ty + i * 8;
    Vt[((size_t)h * VD + d) * S_LEN + s0 + p] = t[tx][ty + i * 8];
  }
}

// ---------------------------------------------------------------------------
// Split-2 MFMA flash attention (exact R9 structure; bf16 partials).
// Block = 4 waves x 16 q = 64 rows; KVBLK=32 double-buffered (40 KB LDS ->
// 4 blocks/CU); split s takes tiles j == s (mod 2) -> t+1 tiles each;
// grid 1024. Co-resident blocks {z,z+8,z+16,z+24} sum to 66 intervals.
// Writes UNNORMALIZED bf16 partials + (m,l); combine2 merges.
// ---------------------------------------------------------------------------
__global__ __launch_bounds__(256, 4) void flash_attn(const unsigned short* __restrict__ Q,   // (S,3072) pre-scaled
                                                     const unsigned short* __restrict__ Kb,  // (H,S,192)
                                                     const unsigned short* __restrict__ Vt,  // (H,128,S) permuted
                                                     unsigned short* __restrict__ Pb,        // (S,2,16,128) bf16
                                                     float2* __restrict__ mlb) {             // (S,2,16) {m,l}
  __shared__ unsigned short Ks[2][32 * QHD];   // 2 x 12 KB
  __shared__ unsigned short Vs[2][VD * 32];    // 2 x  8 KB
  const int tid = threadIdx.x;
  const int wave = tid >> 6, lane = tid & 63;
  const int g = lane >> 4, col = lane & 15;
  const int lin = (int)blockIdx.x;                    // 0..1023
  const int h = ((lin & 7) << 1) | ((lin >> 3) & 1);  // XCD owns a head pair
  const int s = (lin >> 4) & 1;                       // k-split
  const int z = lin >> 5;                             // 0..31
  int t;                                              // balanced qblock mapping
  if (z < 8) t = 31 - z;
  else if (z < 16) t = z - 8;
  else if (z < 24) t = 39 - z;
  else t = z - 16;
  const int qw = t * 64 + wave * 16;
  const int qr = qw + col;

  bf16x8 qf[6];
  {
    const unsigned short* qrow = Q + (size_t)qr * (N_HEADS * QHD) + h * QHD + g * 8;
#pragma unroll
    for (int i = 0; i < 6; ++i) qf[i] = *(const bf16x8*)(qrow + i * 32);
  }

  const unsigned short* KbH = Kb + (size_t)h * S_LEN * QHD;
  const unsigned short* VtH = Vt + (size_t)h * VD * S_LEN;

  // staging source offsets (pre-swizzled slots; fixed across tiles)
  int eK[3], eV[2];
#pragma unroll
  for (int i = 0; i < 3; ++i) {                 // 768 K chunks of 16B
    const int c = i * 256 + tid;
    const int r = c / 24, sl = c - r * 24;
    eK[i] = r * QHD + (((sl & 24) | ((sl & 7) ^ (r & 7)))) * 8;
  }
#pragma unroll
  for (int i = 0; i < 2; ++i) {                 // 512 V chunks of 16B
    const int c = i * 256 + tid;
    const int d = c >> 2, sl = c & 3;
    eV[i] = d * S_LEN + ((sl ^ (d & 3))) * 8;
  }

  f32x4 o[8];
#pragma unroll
  for (int i = 0; i < 8; ++i) o[i] = (f32x4){0.f, 0.f, 0.f, 0.f};
  float m = -1e30f, l = 0.f;

  const int nT = t + 1;  // tiles j = 2*it + s

  // prologue: stage tile j=s into buffer 0
  {
    const unsigned short* kp = KbH + (size_t)s * 32 * QHD;
    const unsigned short* vp = VtH + s * 32;
#pragma unroll
    for (int i = 0; i < 3; ++i) gload_lds16(kp + eK[i], &Ks[0][(i * 256 + tid) * 8]);
#pragma unroll
    for (int i = 0; i < 2; ++i) gload_lds16(vp + eV[i], &Vs[0][(i * 256 + tid) * 8]);
  }

  int xK[6];
#pragma unroll
  for (int i = 0; i < 6; ++i) xK[i] = ((4 * i + g) ^ (col & 7)) * 8;
  const int rbK = col * QHD;
  const int xV = (g ^ (col & 3)) * 8;
  const int rbV = col * 32;

  for (int it = 0; it < nT; ++it) {
    __syncthreads();
    if (it + 1 < nT) {
      const int jn = 2 * (it + 1) + s;
      const unsigned short* kp = KbH + (size_t)jn * 32 * QHD;
      const unsigned short* vp = VtH + jn * 32;
      const int b = (it + 1) & 1;
#pragma unroll
      for (int i = 0; i < 3; ++i) gload_lds16(kp + eK[i], &Ks[b][(i * 256 + tid) * 8]);
#pragma unroll
      for (int i = 0; i < 2; ++i) gload_lds16(vp + eV[i], &Vs[b][(i * 256 + tid) * 8]);
    }
    const int k0 = 32 * (2 * it + s);
    if (k0 <= qw + 15) {
      const unsigned short* Ksc = Ks[it & 1];
      const unsigned short* Vsc = Vs[it & 1];

      f32x4 c0 = (f32x4){0.f, 0.f, 0.f, 0.f}, c1 = (f32x4){0.f, 0.f, 0.f, 0.f};
      __builtin_amdgcn_s_setprio(1);
#pragma unroll
      for (int dt = 0; dt < 6; ++dt) {
        const bf16x8 a0 = *(const bf16x8*)(Ksc + rbK + xK[dt]);
        const bf16x8 a1 = *(const bf16x8*)(Ksc + rbK + 16 * QHD + xK[dt]);
        c0 = __builtin_amdgcn_mfma_f32_16x16x32_bf16(a0, qf[dt], c0, 0, 0, 0);
        c1 = __builtin_amdgcn_mfma_f32_16x16x32_bf16(a1, qf[dt], c1, 0, 0, 0);
      }
      __builtin_amdgcn_s_setprio(0);

      // causal mask only on diagonal tiles (k = k0 + 16*frag + 4g + r)
      if (k0 + 31 > qw) {
#pragma unroll
        for (int r = 0; r < 4; ++r) {
          const int kk = k0 + 4 * g + r;
          if (kk > qr) c0[r] = -1e30f;
          if (kk + 16 > qr) c1[r] = -1e30f;
        }
      }
      float bm = fmaxf(fmaxf(fmaxf(c0[0], c0[1]), fmaxf(c0[2], c0[3])),
                       fmaxf(fmaxf(c1[0], c1[1]), fmaxf(c1[2], c1[3])));
      bm = fmaxf(bm, __shfl_xor(bm, 16));
      bm = fmaxf(bm, __shfl_xor(bm, 32));
      const bool skip = __all(bm <= m + 8.f);   // defer-max: p bounded by 2^8
      const float mn = skip ? m : fmaxf(m, bm);
      float ps = 0.f;
      bf16x8 pb;
#pragma unroll
      for (int r = 0; r < 4; ++r) {
        const float p0 = exp2f(c0[r] - mn);
        const float p1 = exp2f(c1[r] - mn);
        ps += p0 + p1;
        pb[r] = (short)f2u_fast(p0);
        pb[4 + r] = (short)f2u_fast(p1);
      }
      ps += __shfl_xor(ps, 16);
      ps += __shfl_xor(ps, 32);
      if (skip) {
        l += ps;
      } else {
        const float corr = exp2f(m - mn);
        l = l * corr + ps;
        m = mn;
#pragma unroll
        for (int i = 0; i < 8; ++i) {
          o[i][0] *= corr; o[i][1] *= corr; o[i][2] *= corr; o[i][3] *= corr;
        }
      }
      __builtin_amdgcn_s_setprio(1);
#pragma unroll
      for (int db = 0; db < 8; ++db) {
        const bf16x8 va = *(const bf16x8*)(Vsc + db * 512 + rbV + xV);
        o[db] = __builtin_amdgcn_mfma_f32_16x16x32_bf16(va, pb, o[db], 0, 0, 0);
      }
      __builtin_amdgcn_s_setprio(0);
    }
  }

  // epilogue: bf16 unnormalized partials + (m,l)
  unsigned short* pr = Pb + (((size_t)qr * 2 + s) * N_HEADS + h) * VD;
#pragma unroll
  for (int db = 0; db < 8; ++db) {
    u16x4 w4;
#pragma unroll
    for (int r = 0; r < 4; ++r) w4[r] = f2u(o[db][r]);
    *(uint2*)(pr + db * 16 + 4 * g) = __builtin_bit_cast(uint2, w4);
  }
  if (g == 0) mlb[((size_t)qr * 2 + s) * N_HEADS + h] = make_float2(m, l);
}

// ---------------------------------------------------------------------------
// Merge the two k-splits: out = (w0*P0 + w1*P1) / (w0*l0 + w1*l1), bf16.
// ---------------------------------------------------------------------------
__global__ __launch_bounds__(256) void combine2(const unsigned short* __restrict__ Pb,
                                                const float2* __restrict__ mlb,
                                                unsigned short* __restrict__ outb) {
  const int idx = blockIdx.x * 256 + threadIdx.x;  // exactly 524288
  const int d8 = idx & 15, hq = idx >> 4;
  const int h = hq & 15, q = hq >> 4;
  const float2 a = mlb[((size_t)q * 2 + 0) * N_HEADS + h];
  const float2 b = mlb[((size_t)q * 2 + 1) * N_HEADS + h];
  const float M = fmaxf(a.x, b.x);
  float wA = exp2f(a.x - M), wB = exp2f(b.x - M);
  const float inv = 1.f / (wA * a.y + wB * b.y);
  wA *= inv; wB *= inv;
  const bf16x8 v0 = *(const bf16x8*)(Pb + (((size_t)q * 2 + 0) * N_HEADS + h) * VD + d8 * 8);
  const bf16x8 v1 = *(const bf16x8*)(Pb + (((size_t)q * 2 + 1) * N_HEADS + h) * VD + d8 * 8);
  u16x4 o0, o1;
#pragma unroll
  for (int e = 0; e < 4; ++e) {
    o0[e] = f2u(u2f((unsigned short)v0[e]) * wA + u2f((unsigned short)v1[e]) * wB);
    o1[e] = f2u(u2f((unsigned short)v0[4 + e]) * wA + u2f((unsigned short)v1[4 + e]) * wB);
  }
  unsigned short* dst = outb + ((size_t)q * N_HEADS + h) * VD + d8 * 8;
  *(uint2*)(dst) = __builtin_bit_cast(uint2, o0);
  *(uint2*)(dst + 4) = __builtin_bit_cast(uint2, o1);
}

// ---------------------------------------------------------------------------
extern "C" void kernel_launch(void* const* d_in, const int* in_sizes, int n_in,
                              void* d_out, int out_size, void* d_ws, size_t ws_size,
                              hipStream_t stream) {
  const float* hidden    = (const float*)d_in[0];
  const int*   pos       = (const int*)d_in[1];
  const float* q_a_w     = (const float*)d_in[2];
  const float* q_a_ln_w  = (const float*)d_in[3];
  const float* q_b_w     = (const float*)d_in[4];
  const float* kv_a_w    = (const float*)d_in[5];
  const float* kv_a_ln_w = (const float*)d_in[6];
  const float* kv_b_w    = (const float*)d_in[7];
  const float* o_w       = (const float*)d_in[8];
  float* out = (float*)d_out;
  (void)in_sizes; (void)n_in; (void)out_size; (void)ws_size;

  // workspace layout (bytes); total ~94 MB
  char* base = (char*)d_ws;
  unsigned short* qbuf  = (unsigned short*)(base);              // S*3072 bf16  12.58MB
  unsigned short* kvbuf = (unsigned short*)(base + 12582912);   // S*4096 bf16  (V half)
  unsigned short* Pbuf  = (unsigned short*)(base + 12582912);   //   overlay: S*2*16*128 bf16 = 16.78MB (kvbuf dead)
  float*          ac    = (float*)(base + 29360128);            // S*2112 f32   17.30MB
  unsigned short* qan   = (unsigned short*)(base + 46661632);   // S*1536 bf16   6.29MB
  float2*         mlb   = (float2*)(base + 46661632);           //   overlay: S*2*16 float2 = 0.5MB (qan dead)
  unsigned short* ckvn  = (unsigned short*)(base + 52953088);   // S*512 bf16    2.10MB
  unsigned short* Hb    = (unsigned short*)(base + 55050240);   // S*2048 bf16   8.39MB
  unsigned short* Vt    = (unsigned short*)(base + 55050240);   //   overlay (Hb dead after a-proj)
  unsigned short* wbuf  = (unsigned short*)(base + 63438848);   // 4.72M bf16    9.44MB
  unsigned short* attnb = (unsigned short*)(base + 72876032);   // S*2048 bf16   8.39MB
  unsigned short* Kb    = (unsigned short*)(base + 81264640);   // 16*S*192 bf16 12.58MB

  const dim3 b256(256);
  // 192^-0.5 * log2(e): scores come out of QK^T directly in log2 domain
  const float qscale = 0.07216878364870323f * 1.4426950408889634f;

  conv_bf16<<<2048, b256, 0, stream>>>(hidden, Hb, (S_LEN * D_MODEL) / 4, 1.f);

  // fused a-proj: W = [q_a_w ; kv_a_w] (2112 x 2048), C = ac f32 (S x 2112)
  conv2_bf16<<<2048, b256, 0, stream>>>(q_a_w, (Q_LORA * D_MODEL) / 4,
                                        kv_a_w, (AC_W * D_MODEL) / 4, wbuf);
  gemm_mfma<0><<<dim3(AC_W / 64, S_LEN / 128), b256, 0, stream>>>(Hb, wbuf, ac, nullptr, AC_W, D_MODEL);

  // fused double rmsnorm (q_a and kv slices)
  rmsnorm2_kernel<<<dim3(S_LEN, 2), b256, 0, stream>>>(ac, q_a_ln_w, kv_a_ln_w, qan, ckvn);

  // qbuf = qan @ (qscale*q_b_w)^T   (bf16 out)
  conv_bf16<<<2048, b256, 0, stream>>>(q_b_w, wbuf, (N_HEADS * QHD * Q_LORA) / 4, qscale);
  gemm_mfma<1><<<dim3(N_HEADS * QHD / 64, S_LEN / 128), b256, 0, stream>>>(qan, wbuf, qbuf, nullptr, N_HEADS * QHD, Q_LORA);

  // kv_b: k_nope -> Kb directly, values -> kvbuf
  conv_bf16<<<2048, b256, 0, stream>>>(kv_b_w, wbuf, (N_HEADS * 256 * KV_LORA) / 4, 1.f);
  gemm_mfma<2><<<dim3(N_HEADS * 256 / 64, S_LEN / 128), b256, 0, stream>>>(ckvn, wbuf, kvbuf, Kb, N_HEADS * 256, KV_LORA);

  // rope: qbuf q_pe in place; k_pe -> Kb cols 128..192 (all heads)
  rope_kernel<<<S_LEN, 32, 0, stream>>>(qbuf, ac, Kb, pos);

  build_vt<<<dim3(S_LEN / 32, VD / 32, N_HEADS), b256, 0, stream>>>(kvbuf, Vt);

  // split-2 flash (bf16 partials over kvbuf region — dead; ml over qan — dead)
  flash_attn<<<dim3(1024), b256, 0, stream>>>(qbuf, Kb, Vt, Pbuf, mlb);
  combine2<<<2048, b256, 0, stream>>>(Pbuf, mlb, attnb);

  conv_bf16<<<2048, b256, 0, stream>>>(o_w, wbuf, (D_MODEL * N_HEADS * VD) / 4, 1.f);
  gemm_mfma<0><<<dim3(D_MODEL / 64, S_LEN / 128), b256, 0, stream>>>(attnb, wbuf, out, nullptr, D_MODEL, N_HEADS * VD);
}

// Round 13
// 195.895 us; speedup vs baseline: 1.1191x; 1.0448x over previous
//
#include <hip/hip_runtime.h>
#include <hip/hip_bf16.h>
#include <cmath>

#define S_LEN 2048
#define D_MODEL 2048
#define N_HEADS 16
#define Q_LORA 1536
#define KV_LORA 512
#define NOPE 128
#define ROPE_D 64
#define VD 128
#define QHD 192
#define AC_W 2112  // fused a-proj output width: 1536 q_a + 576 ckv

typedef __attribute__((ext_vector_type(8))) short bf16x8;
typedef __attribute__((ext_vector_type(4))) float f32x4;
typedef __attribute__((ext_vector_type(4))) unsigned short u16x4;

static __device__ __forceinline__ unsigned short f2u(float x) {
  union { float f; unsigned u; } v; v.f = x;
  unsigned r = v.u + 0x7fffu + ((v.u >> 16) & 1u);  // RNE
  return (unsigned short)(r >> 16);
}
static __device__ __forceinline__ unsigned short f2u_fast(float x) {  // round-half-up, x>=0
  union { float f; unsigned u; } v; v.f = x;
  return (unsigned short)((v.u + 0x8000u) >> 16);
}
static __device__ __forceinline__ float u2f(unsigned short x) {
  union { unsigned u; float f; } v; v.u = ((unsigned)x) << 16;
  return v.f;
}

#define AS1 __attribute__((address_space(1)))
#define AS3 __attribute__((address_space(3)))
static __device__ __forceinline__ void gload_lds16(const unsigned short* g, unsigned short* l) {
  __builtin_amdgcn_global_load_lds((const AS1 unsigned int*)g, (AS3 unsigned int*)l, 16, 0, 0);
}

// ---------------------------------------------------------------------------
// f32 -> bf16 convert (optionally scaled). n4 = elements/4.
// ---------------------------------------------------------------------------
__global__ __launch_bounds__(256) void conv_bf16(const float* __restrict__ src,
                                                 unsigned short* __restrict__ dst,
                                                 int n4, float scale) {
  for (int i = blockIdx.x * 256 + threadIdx.x; i < n4; i += gridDim.x * 256) {
    const float4 v = ((const float4*)src)[i];
    u16x4 o;
    o[0] = f2u(v.x * scale); o[1] = f2u(v.y * scale);
    o[2] = f2u(v.z * scale); o[3] = f2u(v.w * scale);
    ((u16x4*)dst)[i] = o;
  }
}

// stage-1 conversions in one launch: hidden -> Hb; [q_a_w ; kv_a_w] -> wbuf
__global__ __launch_bounds__(256) void conv_stage1(const float* __restrict__ hidden,
                                                   const float* __restrict__ qaw,
                                                   const float* __restrict__ kvaw,
                                                   unsigned short* __restrict__ Hb,
                                                   unsigned short* __restrict__ wbuf) {
  const int nH = (S_LEN * D_MODEL) / 4;
  const int nQ = (Q_LORA * D_MODEL) / 4;
  const int nT = nH + nQ + ((KV_LORA + ROPE_D) * D_MODEL) / 4;
  for (int i = blockIdx.x * 256 + threadIdx.x; i < nT; i += gridDim.x * 256) {
    float4 v;
    unsigned short* dst;
    int o;
    if (i < nH) {
      v = ((const float4*)hidden)[i]; dst = Hb; o = i;
    } else {
      o = i - nH;
      v = (o < nQ) ? ((const float4*)qaw)[o] : ((const float4*)kvaw)[o - nQ];
      dst = wbuf;
    }
    u16x4 u;
    u[0] = f2u(v.x); u[1] = f2u(v.y); u[2] = f2u(v.z); u[3] = f2u(v.w);
    ((u16x4*)dst)[o] = u;
  }
}

// stage-2 conversions in one launch: qscale*q_b_w -> wbuf; kv_b_w -> kvbw
__global__ __launch_bounds__(256) void conv_stage2(const float* __restrict__ qbw,
                                                   const float* __restrict__ kvbsrc,
                                                   unsigned short* __restrict__ wbuf,
                                                   unsigned short* __restrict__ kvbw,
                                                   float qscale) {
  const int nQB = (N_HEADS * QHD * Q_LORA) / 4;
  const int nT = nQB + (N_HEADS * 256 * KV_LORA) / 4;
  for (int i = blockIdx.x * 256 + threadIdx.x; i < nT; i += gridDim.x * 256) {
    u16x4 u;
    if (i < nQB) {
      const float4 v = ((const float4*)qbw)[i];
      u[0] = f2u(v.x * qscale); u[1] = f2u(v.y * qscale);
      u[2] = f2u(v.z * qscale); u[3] = f2u(v.w * qscale);
      ((u16x4*)wbuf)[i] = u;
    } else {
      const int o = i - nQB;
      const float4 v = ((const float4*)kvbsrc)[o];
      u[0] = f2u(v.x); u[1] = f2u(v.y); u[2] = f2u(v.z); u[3] = f2u(v.w);
      ((u16x4*)kvbw)[o] = u;
    }
  }
}

// ---------------------------------------------------------------------------
// bf16 MFMA GEMM: C[M,N] = A[M,K] @ W[N,K]^T. 128x64 tile, BK=64, 4 waves
// (each 64x32 output), double-buffered LDS (48 KB), one barrier per 64-k
// step, XOR-swizzled (pre-swizzled global source + same XOR on ds_read).
// MODE 0: f32 C. MODE 1: bf16 C.
// MODE 2: kv-split — col=h*256+d; d<128 -> C2 = Kb(h,row,d); d>=128 ->
//   Cv = Vt(h, d-128, perm(s)) DIRECTLY (build_vt fused into the epilogue).
//   perm(s) = ((s&15)>>2)*8 + ((s>>4)&1)*4 + (s&3) maps the 4 consecutive
//   rows (row0 == 0 mod 4) to 4 consecutive positions -> single 8B store.
// ---------------------------------------------------------------------------
template <int MODE>
__global__ __launch_bounds__(256) void gemm_mfma(const unsigned short* __restrict__ A,
                                                 const unsigned short* __restrict__ W,
                                                 void* __restrict__ Cv,
                                                 unsigned short* __restrict__ C2,
                                                 int N, int K) {
  __shared__ unsigned short As[2][8192];  // 128 x 64 bf16
  __shared__ unsigned short Ws[2][4096];  //  64 x 64 bf16
  const int tid = threadIdx.x;
  const int wave = tid >> 6, lane = tid & 63;
  const int col16 = lane & 15, g = lane >> 4;
  const int arow = blockIdx.y * 128, wrow = blockIdx.x * 64;
  const int wm = (wave >> 1) * 64, wn = (wave & 1) * 32;

  const unsigned short* gA[4];
  const unsigned short* gW[2];
  int dA[4], dW[2];
#pragma unroll
  for (int i = 0; i < 4; ++i) {
    const int c = i * 256 + tid;
    const int r = c >> 3, sl = c & 7;
    gA[i] = A + (size_t)(arow + r) * K + (sl ^ (r & 7)) * 8;
    dA[i] = c * 8;
  }
#pragma unroll
  for (int i = 0; i < 2; ++i) {
    const int c = i * 256 + tid;
    const int r = c >> 3, sl = c & 7;
    gW[i] = W + (size_t)(wrow + r) * K + (sl ^ (r & 7)) * 8;
    dW[i] = c * 8;
  }

  f32x4 acc[4][2];
#pragma unroll
  for (int i = 0; i < 4; ++i)
#pragma unroll
    for (int j = 0; j < 2; ++j) acc[i][j] = (f32x4){0.f, 0.f, 0.f, 0.f};

#pragma unroll
  for (int i = 0; i < 4; ++i) gload_lds16(gA[i], &As[0][dA[i]]);
#pragma unroll
  for (int i = 0; i < 2; ++i) gload_lds16(gW[i], &Ws[0][dW[i]]);

  int cur = 0;
  for (int k0 = 0; k0 < K; k0 += 64) {
    __syncthreads();
    if (k0 + 64 < K) {
      const int b = cur ^ 1, kk = k0 + 64;
#pragma unroll
      for (int i = 0; i < 4; ++i) gload_lds16(gA[i] + kk, &As[b][dA[i]]);
#pragma unroll
      for (int i = 0; i < 2; ++i) gload_lds16(gW[i] + kk, &Ws[b][dW[i]]);
    }
#pragma unroll
    for (int kh = 0; kh < 2; ++kh) {
      bf16x8 af[4], bfr[2];
#pragma unroll
      for (int i = 0; i < 4; ++i) {
        const int row = wm + i * 16 + col16;
        af[i] = *(const bf16x8*)(&As[cur][row * 64 + (((kh * 4 + g) ^ (row & 7)) * 8)]);
      }
#pragma unroll
      for (int j = 0; j < 2; ++j) {
        const int row = wn + j * 16 + col16;
        bfr[j] = *(const bf16x8*)(&Ws[cur][row * 64 + (((kh * 4 + g) ^ (row & 7)) * 8)]);
      }
#pragma unroll
      for (int i = 0; i < 4; ++i)
#pragma unroll
        for (int j = 0; j < 2; ++j)
          acc[i][j] = __builtin_amdgcn_mfma_f32_16x16x32_bf16(af[i], bfr[j], acc[i][j], 0, 0, 0);
    }
    cur ^= 1;
  }

#pragma unroll
  for (int i = 0; i < 4; ++i)
#pragma unroll
    for (int j = 0; j < 2; ++j) {
      const int col = wrow + wn + j * 16 + col16;
      const int row0 = arow + wm + i * 16 + g * 4;
      if constexpr (MODE == 0) {
#pragma unroll
        for (int r = 0; r < 4; ++r)
          ((float*)Cv)[(size_t)(row0 + r) * N + col] = acc[i][j][r];
      } else if constexpr (MODE == 1) {
#pragma unroll
        for (int r = 0; r < 4; ++r)
          ((unsigned short*)Cv)[(size_t)(row0 + r) * N + col] = f2u(acc[i][j][r]);
      } else {
        const int hh = col >> 8, d = col & 255;
        if (d < NOPE) {
#pragma unroll
          for (int r = 0; r < 4; ++r)
            C2[((size_t)hh * S_LEN + row0 + r) * QHD + d] = f2u(acc[i][j][r]);
        } else {
          // fused build_vt: Vt(h, d-128, (row0&~31) + perm(row0&31) + r)
          const int dv = d - NOPE;
          const int p0 = ((row0 & 15) >> 2) * 8 + ((row0 >> 4) & 1) * 4;
          u16x4 w4;
#pragma unroll
          for (int r = 0; r < 4; ++r) w4[r] = f2u(acc[i][j][r]);
          *(uint2*)((unsigned short*)Cv + ((size_t)hh * VD + dv) * S_LEN + (row0 & ~31) + p0) =
              __builtin_bit_cast(uint2, w4);
        }
      }
    }
}

// ---------------------------------------------------------------------------
// Fused RMSNorm: blockIdx.y = 0 -> q_a slice (dim 1536), 1 -> kv slice (512).
// f32 in (ac, ld 2112) -> bf16 out.
// ---------------------------------------------------------------------------
__global__ __launch_bounds__(256) void rmsnorm2_kernel(const float* __restrict__ ac,
                                                       const float* __restrict__ wq,
                                                       const float* __restrict__ wkv,
                                                       unsigned short* __restrict__ qan,
                                                       unsigned short* __restrict__ ckvn) {
  const int row = blockIdx.x;
  const bool kv = blockIdx.y != 0;
  const float* x = ac + (size_t)row * AC_W + (kv ? Q_LORA : 0);
  const float* w = kv ? wkv : wq;
  unsigned short* dst = kv ? (ckvn + (size_t)row * KV_LORA) : (qan + (size_t)row * Q_LORA);
  const int dim = kv ? KV_LORA : Q_LORA;
  float ss = 0.f;
  for (int i = threadIdx.x; i < dim; i += 256) {
    float v = x[i];
    ss += v * v;
  }
#pragma unroll
  for (int off = 32; off; off >>= 1) ss += __shfl_xor(ss, off);
  __shared__ float red[4];
  const int wv = threadIdx.x >> 6, ln = threadIdx.x & 63;
  if (ln == 0) red[wv] = ss;
  __syncthreads();
  const float tot = red[0] + red[1] + red[2] + red[3];
  const float scale = rsqrtf(tot / (float)dim + 1e-6f);
  for (int i = threadIdx.x; i < dim; i += 256) {
    dst[i] = f2u(w[i] * (x[i] * scale));
  }
}

// ---------------------------------------------------------------------------
// RoPE: q_pe slices of bf16 qbuf in place; k_pe -> broadcast into Kb.
// ---------------------------------------------------------------------------
__global__ void rope_kernel(unsigned short* __restrict__ q, const float* __restrict__ ac,
                            unsigned short* __restrict__ Kb, const int* __restrict__ pos_ids) {
  const int s = blockIdx.x;
  const int j = threadIdx.x;  // 0..31
  const float t = (float)pos_ids[s];
  const float invf = powf(50000.0f, -(float)(2 * j) / 64.0f);
  const float ang = t * invf;
  const float c = cosf(ang), sn = sinf(ang);
  for (int h = 0; h < N_HEADS; ++h) {
    unsigned short* base = q + (size_t)s * (N_HEADS * QHD) + h * QHD + NOPE;
    const float x0 = u2f(base[2 * j]), x1 = u2f(base[2 * j + 1]);
    __syncthreads();
    base[j] = f2u(x0 * c - x1 * sn);
    base[32 + j] = f2u(x1 * c + x0 * sn);
    __syncthreads();
  }
  const float* kb = ac + (size_t)s * AC_W + 2048;
  const unsigned short r0 = f2u(kb[2 * j] * c - kb[2 * j + 1] * sn);
  const unsigned short r1 = f2u(kb[2 * j + 1] * c + kb[2 * j] * sn);
#pragma unroll
  for (int h = 0; h < N_HEADS; ++h) {
    unsigned short* kd = Kb + ((size_t)h * S_LEN + s) * QHD + NOPE;
    kd[j] = r0;
    kd[32 + j] = r1;
  }
}

// ---------------------------------------------------------------------------
// Split-2 MFMA flash attention (R9 structure; bf16 partials). Unchanged.
// ---------------------------------------------------------------------------
__global__ __launch_bounds__(256, 4) void flash_attn(const unsigned short* __restrict__ Q,   // (S,3072) pre-scaled
                                                     const unsigned short* __restrict__ Kb,  // (H,S,192)
                                                     const unsigned short* __restrict__ Vt,  // (H,128,S) permuted
                                                     unsigned short* __restrict__ Pb,        // (S,2,16,128) bf16
                                                     float2* __restrict__ mlb) {             // (S,2,16) {m,l}
  __shared__ unsigned short Ks[2][32 * QHD];   // 2 x 12 KB
  __shared__ unsigned short Vs[2][VD * 32];    // 2 x  8 KB
  const int tid = threadIdx.x;
  const int wave = tid >> 6, lane = tid & 63;
  const int g = lane >> 4, col = lane & 15;
  const int lin = (int)blockIdx.x;                    // 0..1023
  const int h = ((lin & 7) << 1) | ((lin >> 3) & 1);  // XCD owns a head pair
  const int s = (lin >> 4) & 1;                       // k-split
  const int z = lin >> 5;                             // 0..31
  int t;                                              // balanced qblock mapping
  if (z < 8) t = 31 - z;
  else if (z < 16) t = z - 8;
  else if (z < 24) t = 39 - z;
  else t = z - 16;
  const int qw = t * 64 + wave * 16;
  const int qr = qw + col;

  bf16x8 qf[6];
  {
    const unsigned short* qrow = Q + (size_t)qr * (N_HEADS * QHD) + h * QHD + g * 8;
#pragma unroll
    for (int i = 0; i < 6; ++i) qf[i] = *(const bf16x8*)(qrow + i * 32);
  }

  const unsigned short* KbH = Kb + (size_t)h * S_LEN * QHD;
  const unsigned short* VtH = Vt + (size_t)h * VD * S_LEN;

  // staging source offsets (pre-swizzled slots; fixed across tiles)
  int eK[3], eV[2];
#pragma unroll
  for (int i = 0; i < 3; ++i) {                 // 768 K chunks of 16B
    const int c = i * 256 + tid;
    const int r = c / 24, sl = c - r * 24;
    eK[i] = r * QHD + (((sl & 24) | ((sl & 7) ^ (r & 7)))) * 8;
  }
#pragma unroll
  for (int i = 0; i < 2; ++i) {                 // 512 V chunks of 16B
    const int c = i * 256 + tid;
    const int d = c >> 2, sl = c & 3;
    eV[i] = d * S_LEN + ((sl ^ (d & 3))) * 8;
  }

  f32x4 o[8];
#pragma unroll
  for (int i = 0; i < 8; ++i) o[i] = (f32x4){0.f, 0.f, 0.f, 0.f};
  float m = -1e30f, l = 0.f;

  const int nT = t + 1;  // tiles j = 2*it + s

  // prologue: stage tile j=s into buffer 0
  {
    const unsigned short* kp = KbH + (size_t)s * 32 * QHD;
    const unsigned short* vp = VtH + s * 32;
#pragma unroll
    for (int i = 0; i < 3; ++i) gload_lds16(kp + eK[i], &Ks[0][(i * 256 + tid) * 8]);
#pragma unroll
    for (int i = 0; i < 2; ++i) gload_lds16(vp + eV[i], &Vs[0][(i * 256 + tid) * 8]);
  }

  int xK[6];
#pragma unroll
  for (int i = 0; i < 6; ++i) xK[i] = ((4 * i + g) ^ (col & 7)) * 8;
  const int rbK = col * QHD;
  const int xV = (g ^ (col & 3)) * 8;
  const int rbV = col * 32;

  for (int it = 0; it < nT; ++it) {
    __syncthreads();
    if (it + 1 < nT) {
      const int jn = 2 * (it + 1) + s;
      const unsigned short* kp = KbH + (size_t)jn * 32 * QHD;
      const unsigned short* vp = VtH + jn * 32;
      const int b = (it + 1) & 1;
#pragma unroll
      for (int i = 0; i < 3; ++i) gload_lds16(kp + eK[i], &Ks[b][(i * 256 + tid) * 8]);
#pragma unroll
      for (int i = 0; i < 2; ++i) gload_lds16(vp + eV[i], &Vs[b][(i * 256 + tid) * 8]);
    }
    const int k0 = 32 * (2 * it + s);
    if (k0 <= qw + 15) {
      const unsigned short* Ksc = Ks[it & 1];
      const unsigned short* Vsc = Vs[it & 1];

      f32x4 c0 = (f32x4){0.f, 0.f, 0.f, 0.f}, c1 = (f32x4){0.f, 0.f, 0.f, 0.f};
      __builtin_amdgcn_s_setprio(1);
#pragma unroll
      for (int dt = 0; dt < 6; ++dt) {
        const bf16x8 a0 = *(const bf16x8*)(Ksc + rbK + xK[dt]);
        const bf16x8 a1 = *(const bf16x8*)(Ksc + rbK + 16 * QHD + xK[dt]);
        c0 = __builtin_amdgcn_mfma_f32_16x16x32_bf16(a0, qf[dt], c0, 0, 0, 0);
        c1 = __builtin_amdgcn_mfma_f32_16x16x32_bf16(a1, qf[dt], c1, 0, 0, 0);
      }
      __builtin_amdgcn_s_setprio(0);

      // causal mask only on diagonal tiles (k = k0 + 16*frag + 4g + r)
      if (k0 + 31 > qw) {
#pragma unroll
        for (int r = 0; r < 4; ++r) {
          const int kk = k0 + 4 * g + r;
          if (kk > qr) c0[r] = -1e30f;
          if (kk + 16 > qr) c1[r] = -1e30f;
        }
      }
      float bm = fmaxf(fmaxf(fmaxf(c0[0], c0[1]), fmaxf(c0[2], c0[3])),
                       fmaxf(fmaxf(c1[0], c1[1]), fmaxf(c1[2], c1[3])));
      bm = fmaxf(bm, __shfl_xor(bm, 16));
      bm = fmaxf(bm, __shfl_xor(bm, 32));
      const bool skip = __all(bm <= m + 8.f);   // defer-max: p bounded by 2^8
      const float mn = skip ? m : fmaxf(m, bm);
      float ps = 0.f;
      bf16x8 pb;
#pragma unroll
      for (int r = 0; r < 4; ++r) {
        const float p0 = exp2f(c0[r] - mn);
        const float p1 = exp2f(c1[r] - mn);
        ps += p0 + p1;
        pb[r] = (short)f2u_fast(p0);
        pb[4 + r] = (short)f2u_fast(p1);
      }
      ps += __shfl_xor(ps, 16);
      ps += __shfl_xor(ps, 32);
      if (skip) {
        l += ps;
      } else {
        const float corr = exp2f(m - mn);
        l = l * corr + ps;
        m = mn;
#pragma unroll
        for (int i = 0; i < 8; ++i) {
          o[i][0] *= corr; o[i][1] *= corr; o[i][2] *= corr; o[i][3] *= corr;
        }
      }
      __builtin_amdgcn_s_setprio(1);
#pragma unroll
      for (int db = 0; db < 8; ++db) {
        const bf16x8 va = *(const bf16x8*)(Vsc + db * 512 + rbV + xV);
        o[db] = __builtin_amdgcn_mfma_f32_16x16x32_bf16(va, pb, o[db], 0, 0, 0);
      }
      __builtin_amdgcn_s_setprio(0);
    }
  }

  // epilogue: bf16 unnormalized partials + (m,l)
  unsigned short* pr = Pb + (((size_t)qr * 2 + s) * N_HEADS + h) * VD;
#pragma unroll
  for (int db = 0; db < 8; ++db) {
    u16x4 w4;
#pragma unroll
    for (int r = 0; r < 4; ++r) w4[r] = f2u(o[db][r]);
    *(uint2*)(pr + db * 16 + 4 * g) = __builtin_bit_cast(uint2, w4);
  }
  if (g == 0) mlb[((size_t)qr * 2 + s) * N_HEADS + h] = make_float2(m, l);
}

// ---------------------------------------------------------------------------
// Merge the two k-splits: out = (w0*P0 + w1*P1) / (w0*l0 + w1*l1), bf16.
// ---------------------------------------------------------------------------
__global__ __launch_bounds__(256) void combine2(const unsigned short* __restrict__ Pb,
                                                const float2* __restrict__ mlb,
                                                unsigned short* __restrict__ outb) {
  const int idx = blockIdx.x * 256 + threadIdx.x;  // exactly 524288
  const int d8 = idx & 15, hq = idx >> 4;
  const int h = hq & 15, q = hq >> 4;
  const float2 a = mlb[((size_t)q * 2 + 0) * N_HEADS + h];
  const float2 b = mlb[((size_t)q * 2 + 1) * N_HEADS + h];
  const float M = fmaxf(a.x, b.x);
  float wA = exp2f(a.x - M), wB = exp2f(b.x - M);
  const float inv = 1.f / (wA * a.y + wB * b.y);
  wA *= inv; wB *= inv;
  const bf16x8 v0 = *(const bf16x8*)(Pb + (((size_t)q * 2 + 0) * N_HEADS + h) * VD + d8 * 8);
  const bf16x8 v1 = *(const bf16x8*)(Pb + (((size_t)q * 2 + 1) * N_HEADS + h) * VD + d8 * 8);
  u16x4 o0, o1;
#pragma unroll
  for (int e = 0; e < 4; ++e) {
    o0[e] = f2u(u2f((unsigned short)v0[e]) * wA + u2f((unsigned short)v1[e]) * wB);
    o1[e] = f2u(u2f((unsigned short)v0[4 + e]) * wA + u2f((unsigned short)v1[4 + e]) * wB);
  }
  unsigned short* dst = outb + ((size_t)q * N_HEADS + h) * VD + d8 * 8;
  *(uint2*)(dst) = __builtin_bit_cast(uint2, o0);
  *(uint2*)(dst + 4) = __builtin_bit_cast(uint2, o1);
}

// ---------------------------------------------------------------------------
extern "C" void kernel_launch(void* const* d_in, const int* in_sizes, int n_in,
                              void* d_out, int out_size, void* d_ws, size_t ws_size,
                              hipStream_t stream) {
  const float* hidden    = (const float*)d_in[0];
  const int*   pos       = (const int*)d_in[1];
  const float* q_a_w     = (const float*)d_in[2];
  const float* q_a_ln_w  = (const float*)d_in[3];
  const float* q_b_w     = (const float*)d_in[4];
  const float* kv_a_w    = (const float*)d_in[5];
  const float* kv_a_ln_w = (const float*)d_in[6];
  const float* kv_b_w    = (const float*)d_in[7];
  const float* o_w       = (const float*)d_in[8];
  float* out = (float*)d_out;
  (void)in_sizes; (void)n_in; (void)out_size; (void)ws_size;

  // workspace layout (bytes); total ~94 MB
  char* base = (char*)d_ws;
  unsigned short* qbuf  = (unsigned short*)(base);              // S*3072 bf16  12.58MB
  unsigned short* Pbuf  = (unsigned short*)(base + 12582912);   // S*2*16*128 bf16 = 16.78MB
  float*          ac    = (float*)(base + 29360128);            // S*2112 f32   17.30MB
  unsigned short* qan   = (unsigned short*)(base + 46661632);   // S*1536 bf16   6.29MB
  float2*         mlb   = (float2*)(base + 46661632);           //   overlay: S*2*16 float2 (qan dead by flash)
  unsigned short* ckvn  = (unsigned short*)(base + 52953088);   // S*512 bf16    2.10MB
  unsigned short* Hb    = (unsigned short*)(base + 55050240);   // S*2048 bf16   8.39MB
  unsigned short* Vt    = (unsigned short*)(base + 55050240);   //   overlay (Hb dead after a-proj)
  unsigned short* wbuf  = (unsigned short*)(base + 63438848);   // 4.72M bf16    9.44MB
  unsigned short* attnb = (unsigned short*)(base + 72876032);   // S*2048 bf16   8.39MB
  unsigned short* kvbw  = (unsigned short*)(base + 72876032);   //   overlay: kv_b bf16 (4.19MB, dead before combine2)
  unsigned short* Kb    = (unsigned short*)(base + 81264640);   // 16*S*192 bf16 12.58MB

  const dim3 b256(256);
  // 192^-0.5 * log2(e): scores come out of QK^T directly in log2 domain
  const float qscale = 0.07216878364870323f * 1.4426950408889634f;

  // stage-1 conversions: hidden -> Hb, [q_a_w;kv_a_w] -> wbuf  (one launch)
  conv_stage1<<<2048, b256, 0, stream>>>(hidden, q_a_w, kv_a_w, Hb, wbuf);

  // fused a-proj: C = ac f32 (S x 2112)
  gemm_mfma<0><<<dim3(AC_W / 64, S_LEN / 128), b256, 0, stream>>>(Hb, wbuf, ac, nullptr, AC_W, D_MODEL);

  // fused double rmsnorm (q_a and kv slices)
  rmsnorm2_kernel<<<dim3(S_LEN, 2), b256, 0, stream>>>(ac, q_a_ln_w, kv_a_ln_w, qan, ckvn);

  // stage-2 conversions: qscale*q_b_w -> wbuf, kv_b_w -> kvbw  (one launch)
  conv_stage2<<<2048, b256, 0, stream>>>(q_b_w, kv_b_w, wbuf, kvbw, qscale);

  // qbuf = qan @ (qscale*q_b_w)^T   (bf16 out)
  gemm_mfma<1><<<dim3(N_HEADS * QHD / 64, S_LEN / 128), b256, 0, stream>>>(qan, wbuf, qbuf, nullptr, N_HEADS * QHD, Q_LORA);

  // kv_b: k_nope -> Kb, values -> Vt directly (build_vt fused)
  gemm_mfma<2><<<dim3(N_HEADS * 256 / 64, S_LEN / 128), b256, 0, stream>>>(ckvn, kvbw, Vt, Kb, N_HEADS * 256, KV_LORA);

  // rope: qbuf q_pe in place; k_pe -> Kb cols 128..192 (all heads)
  rope_kernel<<<S_LEN, 32, 0, stream>>>(qbuf, ac, Kb, pos);

  // split-2 flash (bf16 partials; ml over qan — both dead) + combine
  flash_attn<<<dim3(1024), b256, 0, stream>>>(qbuf, Kb, Vt, Pbuf, mlb);
  combine2<<<2048, b256, 0, stream>>>(Pbuf, mlb, attnb);

  // out = attnb @ o_w^T
  conv_bf16<<<2048, b256, 0, stream>>>(o_w, wbuf, (D_MODEL * N_HEADS * VD) / 4, 1.f);
  gemm_mfma<0><<<dim3(D_MODEL / 64, S_LEN / 128), b256, 0, stream>>>(attnb, wbuf, out, nullptr, D_MODEL, N_HEADS * VD);
}

// Round 14
// 189.286 us; speedup vs baseline: 1.1582x; 1.0349x over previous
//
#include <hip/hip_runtime.h>
#include <hip/hip_bf16.h>
#include <cmath>

#define S_LEN 2048
#define D_MODEL 2048
#define N_HEADS 16
#define Q_LORA 1536
#define KV_LORA 512
#define NOPE 128
#define ROPE_D 64
#define VD 128
#define QHD 192
#define AC_W 2112  // fused a-proj output width: 1536 q_a + 576 ckv

typedef __attribute__((ext_vector_type(8))) short bf16x8;
typedef __attribute__((ext_vector_type(4))) float f32x4;
typedef __attribute__((ext_vector_type(4))) unsigned short u16x4;

static __device__ __forceinline__ unsigned short f2u(float x) {
  union { float f; unsigned u; } v; v.f = x;
  unsigned r = v.u + 0x7fffu + ((v.u >> 16) & 1u);  // RNE
  return (unsigned short)(r >> 16);
}
static __device__ __forceinline__ unsigned short f2u_fast(float x) {  // round-half-up, x>=0
  union { float f; unsigned u; } v; v.f = x;
  return (unsigned short)((v.u + 0x8000u) >> 16);
}
static __device__ __forceinline__ float u2f(unsigned short x) {
  union { unsigned u; float f; } v; v.u = ((unsigned)x) << 16;
  return v.f;
}

#define AS1 __attribute__((address_space(1)))
#define AS3 __attribute__((address_space(3)))
static __device__ __forceinline__ void gload_lds16(const unsigned short* g, unsigned short* l) {
  __builtin_amdgcn_global_load_lds((const AS1 unsigned int*)g, (AS3 unsigned int*)l, 16, 0, 0);
}

// ---------------------------------------------------------------------------
// f32 -> bf16 convert (optionally scaled). n4 = elements/4.
// ---------------------------------------------------------------------------
__global__ __launch_bounds__(256) void conv_bf16(const float* __restrict__ src,
                                                 unsigned short* __restrict__ dst,
                                                 int n4, float scale) {
  for (int i = blockIdx.x * 256 + threadIdx.x; i < n4; i += gridDim.x * 256) {
    const float4 v = ((const float4*)src)[i];
    u16x4 o;
    o[0] = f2u(v.x * scale); o[1] = f2u(v.y * scale);
    o[2] = f2u(v.z * scale); o[3] = f2u(v.w * scale);
    ((u16x4*)dst)[i] = o;
  }
}

// stage-1 conversions in one launch: hidden -> Hb; [q_a_w ; kv_a_w] -> wbuf
__global__ __launch_bounds__(256) void conv_stage1(const float* __restrict__ hidden,
                                                   const float* __restrict__ qaw,
                                                   const float* __restrict__ kvaw,
                                                   unsigned short* __restrict__ Hb,
                                                   unsigned short* __restrict__ wbuf) {
  const int nH = (S_LEN * D_MODEL) / 4;
  const int nQ = (Q_LORA * D_MODEL) / 4;
  const int nT = nH + nQ + ((KV_LORA + ROPE_D) * D_MODEL) / 4;
  for (int i = blockIdx.x * 256 + threadIdx.x; i < nT; i += gridDim.x * 256) {
    float4 v;
    unsigned short* dst;
    int o;
    if (i < nH) {
      v = ((const float4*)hidden)[i]; dst = Hb; o = i;
    } else {
      o = i - nH;
      v = (o < nQ) ? ((const float4*)qaw)[o] : ((const float4*)kvaw)[o - nQ];
      dst = wbuf;
    }
    u16x4 u;
    u[0] = f2u(v.x); u[1] = f2u(v.y); u[2] = f2u(v.z); u[3] = f2u(v.w);
    ((u16x4*)dst)[o] = u;
  }
}

// stage-2 conversions in one launch: qscale*q_b_w -> wbuf; kv_b_w -> kvbw
__global__ __launch_bounds__(256) void conv_stage2(const float* __restrict__ qbw,
                                                   const float* __restrict__ kvbsrc,
                                                   unsigned short* __restrict__ wbuf,
                                                   unsigned short* __restrict__ kvbw,
                                                   float qscale) {
  const int nQB = (N_HEADS * QHD * Q_LORA) / 4;
  const int nT = nQB + (N_HEADS * 256 * KV_LORA) / 4;
  for (int i = blockIdx.x * 256 + threadIdx.x; i < nT; i += gridDim.x * 256) {
    u16x4 u;
    if (i < nQB) {
      const float4 v = ((const float4*)qbw)[i];
      u[0] = f2u(v.x * qscale); u[1] = f2u(v.y * qscale);
      u[2] = f2u(v.z * qscale); u[3] = f2u(v.w * qscale);
      ((u16x4*)wbuf)[i] = u;
    } else {
      const int o = i - nQB;
      const float4 v = ((const float4*)kvbsrc)[o];
      u[0] = f2u(v.x); u[1] = f2u(v.y); u[2] = f2u(v.z); u[3] = f2u(v.w);
      ((u16x4*)kvbw)[o] = u;
    }
  }
}

// ---------------------------------------------------------------------------
// bf16 MFMA GEMM: C[M,N] = A[M,K] @ W[N,K]^T. 128x64 tile, BK=64, 4 waves
// (each 64x32 output), double-buffered LDS (48 KB), one barrier per 64-k
// step, XOR-swizzled (pre-swizzled global source + same XOR on ds_read).
// MODE 0: f32 C. MODE 1: bf16 C.
// ---------------------------------------------------------------------------
template <int MODE>
__global__ __launch_bounds__(256) void gemm_mfma(const unsigned short* __restrict__ A,
                                                 const unsigned short* __restrict__ W,
                                                 void* __restrict__ Cv,
                                                 int N, int K) {
  __shared__ unsigned short As[2][8192];  // 128 x 64 bf16
  __shared__ unsigned short Ws[2][4096];  //  64 x 64 bf16
  const int tid = threadIdx.x;
  const int wave = tid >> 6, lane = tid & 63;
  const int col16 = lane & 15, g = lane >> 4;
  const int arow = blockIdx.y * 128, wrow = blockIdx.x * 64;
  const int wm = (wave >> 1) * 64, wn = (wave & 1) * 32;

  const unsigned short* gA[4];
  const unsigned short* gW[2];
  int dA[4], dW[2];
#pragma unroll
  for (int i = 0; i < 4; ++i) {
    const int c = i * 256 + tid;
    const int r = c >> 3, sl = c & 7;
    gA[i] = A + (size_t)(arow + r) * K + (sl ^ (r & 7)) * 8;
    dA[i] = c * 8;
  }
#pragma unroll
  for (int i = 0; i < 2; ++i) {
    const int c = i * 256 + tid;
    const int r = c >> 3, sl = c & 7;
    gW[i] = W + (size_t)(wrow + r) * K + (sl ^ (r & 7)) * 8;
    dW[i] = c * 8;
  }

  f32x4 acc[4][2];
#pragma unroll
  for (int i = 0; i < 4; ++i)
#pragma unroll
    for (int j = 0; j < 2; ++j) acc[i][j] = (f32x4){0.f, 0.f, 0.f, 0.f};

#pragma unroll
  for (int i = 0; i < 4; ++i) gload_lds16(gA[i], &As[0][dA[i]]);
#pragma unroll
  for (int i = 0; i < 2; ++i) gload_lds16(gW[i], &Ws[0][dW[i]]);

  int cur = 0;
  for (int k0 = 0; k0 < K; k0 += 64) {
    __syncthreads();
    if (k0 + 64 < K) {
      const int b = cur ^ 1, kk = k0 + 64;
#pragma unroll
      for (int i = 0; i < 4; ++i) gload_lds16(gA[i] + kk, &As[b][dA[i]]);
#pragma unroll
      for (int i = 0; i < 2; ++i) gload_lds16(gW[i] + kk, &Ws[b][dW[i]]);
    }
#pragma unroll
    for (int kh = 0; kh < 2; ++kh) {
      bf16x8 af[4], bfr[2];
#pragma unroll
      for (int i = 0; i < 4; ++i) {
        const int row = wm + i * 16 + col16;
        af[i] = *(const bf16x8*)(&As[cur][row * 64 + (((kh * 4 + g) ^ (row & 7)) * 8)]);
      }
#pragma unroll
      for (int j = 0; j < 2; ++j) {
        const int row = wn + j * 16 + col16;
        bfr[j] = *(const bf16x8*)(&Ws[cur][row * 64 + (((kh * 4 + g) ^ (row & 7)) * 8)]);
      }
#pragma unroll
      for (int i = 0; i < 4; ++i)
#pragma unroll
        for (int j = 0; j < 2; ++j)
          acc[i][j] = __builtin_amdgcn_mfma_f32_16x16x32_bf16(af[i], bfr[j], acc[i][j], 0, 0, 0);
    }
    cur ^= 1;
  }

#pragma unroll
  for (int i = 0; i < 4; ++i)
#pragma unroll
    for (int j = 0; j < 2; ++j) {
      const int col = wrow + wn + j * 16 + col16;
      const int row0 = arow + wm + i * 16 + g * 4;
#pragma unroll
      for (int r = 0; r < 4; ++r) {
        if constexpr (MODE == 0)
          ((float*)Cv)[(size_t)(row0 + r) * N + col] = acc[i][j][r];
        else
          ((unsigned short*)Cv)[(size_t)(row0 + r) * N + col] = f2u(acc[i][j][r]);
      }
    }
}

// ---------------------------------------------------------------------------
// Merged q_b + kv_b GEMM (independent problems, one launch, 1792 blocks).
// bid < 768: q_b (MODE1-like): qbuf = qan @ wbuf^T, N=3072, K=1536.
// bid >= 768: kv_b (MODE2-like): k_nope -> Kb, values -> Vt (fused build_vt
//   with PV permutation), N=4096, K=512.
// Same tile shape (128x64, BK=64) and LDS layout as gemm_mfma.
// ---------------------------------------------------------------------------
__global__ __launch_bounds__(256) void gemm_qkv(const unsigned short* __restrict__ qan,
                                                const unsigned short* __restrict__ wq,
                                                unsigned short* __restrict__ qbuf,
                                                const unsigned short* __restrict__ ckvn,
                                                const unsigned short* __restrict__ wkv,
                                                unsigned short* __restrict__ Kb,
                                                unsigned short* __restrict__ Vt) {
  __shared__ unsigned short As[2][8192];
  __shared__ unsigned short Ws[2][4096];
  const int tid = threadIdx.x;
  const int wave = tid >> 6, lane = tid & 63;
  const int col16 = lane & 15, g = lane >> 4;
  const int bid = (int)blockIdx.x;
  const bool isQ = bid < 768;
  int bx, by;
  if (isQ) { bx = bid % 48; by = bid / 48; }
  else { const int r = bid - 768; bx = r & 63; by = r >> 6; }
  const int K = isQ ? Q_LORA : KV_LORA;
  const unsigned short* A = isQ ? qan : ckvn;
  const unsigned short* W = isQ ? wq : wkv;
  const int arow = by * 128, wrow = bx * 64;
  const int wm = (wave >> 1) * 64, wn = (wave & 1) * 32;

  const unsigned short* gA[4];
  const unsigned short* gW[2];
  int dA[4], dW[2];
#pragma unroll
  for (int i = 0; i < 4; ++i) {
    const int c = i * 256 + tid;
    const int r = c >> 3, sl = c & 7;
    gA[i] = A + (size_t)(arow + r) * K + (sl ^ (r & 7)) * 8;
    dA[i] = c * 8;
  }
#pragma unroll
  for (int i = 0; i < 2; ++i) {
    const int c = i * 256 + tid;
    const int r = c >> 3, sl = c & 7;
    gW[i] = W + (size_t)(wrow + r) * K + (sl ^ (r & 7)) * 8;
    dW[i] = c * 8;
  }

  f32x4 acc[4][2];
#pragma unroll
  for (int i = 0; i < 4; ++i)
#pragma unroll
    for (int j = 0; j < 2; ++j) acc[i][j] = (f32x4){0.f, 0.f, 0.f, 0.f};

#pragma unroll
  for (int i = 0; i < 4; ++i) gload_lds16(gA[i], &As[0][dA[i]]);
#pragma unroll
  for (int i = 0; i < 2; ++i) gload_lds16(gW[i], &Ws[0][dW[i]]);

  int cur = 0;
  for (int k0 = 0; k0 < K; k0 += 64) {
    __syncthreads();
    if (k0 + 64 < K) {
      const int b = cur ^ 1, kk = k0 + 64;
#pragma unroll
      for (int i = 0; i < 4; ++i) gload_lds16(gA[i] + kk, &As[b][dA[i]]);
#pragma unroll
      for (int i = 0; i < 2; ++i) gload_lds16(gW[i] + kk, &Ws[b][dW[i]]);
    }
#pragma unroll
    for (int kh = 0; kh < 2; ++kh) {
      bf16x8 af[4], bfr[2];
#pragma unroll
      for (int i = 0; i < 4; ++i) {
        const int row = wm + i * 16 + col16;
        af[i] = *(const bf16x8*)(&As[cur][row * 64 + (((kh * 4 + g) ^ (row & 7)) * 8)]);
      }
#pragma unroll
      for (int j = 0; j < 2; ++j) {
        const int row = wn + j * 16 + col16;
        bfr[j] = *(const bf16x8*)(&Ws[cur][row * 64 + (((kh * 4 + g) ^ (row & 7)) * 8)]);
      }
#pragma unroll
      for (int i = 0; i < 4; ++i)
#pragma unroll
        for (int j = 0; j < 2; ++j)
          acc[i][j] = __builtin_amdgcn_mfma_f32_16x16x32_bf16(af[i], bfr[j], acc[i][j], 0, 0, 0);
    }
    cur ^= 1;
  }

#pragma unroll
  for (int i = 0; i < 4; ++i)
#pragma unroll
    for (int j = 0; j < 2; ++j) {
      const int col = wrow + wn + j * 16 + col16;
      const int row0 = arow + wm + i * 16 + g * 4;
      if (isQ) {
#pragma unroll
        for (int r = 0; r < 4; ++r)
          qbuf[(size_t)(row0 + r) * (N_HEADS * QHD) + col] = f2u(acc[i][j][r]);
      } else {
        const int hh = col >> 8, d = col & 255;
        if (d < NOPE) {
#pragma unroll
          for (int r = 0; r < 4; ++r)
            Kb[((size_t)hh * S_LEN + row0 + r) * QHD + d] = f2u(acc[i][j][r]);
        } else {
          // fused build_vt: Vt(h, d-128, (row0&~31) + perm(row0&31) + r)
          const int dv = d - NOPE;
          const int p0 = ((row0 & 15) >> 2) * 8 + ((row0 >> 4) & 1) * 4;
          u16x4 w4;
#pragma unroll
          for (int r = 0; r < 4; ++r) w4[r] = f2u(acc[i][j][r]);
          *(uint2*)(Vt + ((size_t)hh * VD + dv) * S_LEN + (row0 & ~31) + p0) =
              __builtin_bit_cast(uint2, w4);
        }
      }
    }
}

// ---------------------------------------------------------------------------
// Fused RMSNorm, bf16 input (ac bf16, ld 2112) -> bf16 out, vectorized x8.
// blockIdx.y = 0 -> q_a slice (1536), 1 -> kv slice (512).
// ---------------------------------------------------------------------------
__global__ __launch_bounds__(256) void rmsnorm2_kernel(const unsigned short* __restrict__ ac,
                                                       const float* __restrict__ wq,
                                                       const float* __restrict__ wkv,
                                                       unsigned short* __restrict__ qan,
                                                       unsigned short* __restrict__ ckvn) {
  const int row = blockIdx.x;
  const bool kv = blockIdx.y != 0;
  const unsigned short* x = ac + (size_t)row * AC_W + (kv ? Q_LORA : 0);
  const float* w = kv ? wkv : wq;
  unsigned short* dst = kv ? (ckvn + (size_t)row * KV_LORA) : (qan + (size_t)row * Q_LORA);
  const int dim = kv ? KV_LORA : Q_LORA;
  float ss = 0.f;
  for (int i0 = threadIdx.x * 8; i0 < dim; i0 += 2048) {
    const bf16x8 v = *(const bf16x8*)(x + i0);
#pragma unroll
    for (int e = 0; e < 8; ++e) {
      const float f = u2f((unsigned short)v[e]);
      ss += f * f;
    }
  }
#pragma unroll
  for (int off = 32; off; off >>= 1) ss += __shfl_xor(ss, off);
  __shared__ float red[4];
  const int wv = threadIdx.x >> 6, ln = threadIdx.x & 63;
  if (ln == 0) red[wv] = ss;
  __syncthreads();
  const float tot = red[0] + red[1] + red[2] + red[3];
  const float scale = rsqrtf(tot / (float)dim + 1e-6f);
  for (int i0 = threadIdx.x * 8; i0 < dim; i0 += 2048) {
    const bf16x8 v = *(const bf16x8*)(x + i0);
    u16x4 o0, o1;
#pragma unroll
    for (int e = 0; e < 4; ++e) {
      o0[e] = f2u(w[i0 + e] * (u2f((unsigned short)v[e]) * scale));
      o1[e] = f2u(w[i0 + 4 + e] * (u2f((unsigned short)v[4 + e]) * scale));
    }
    *(uint2*)(dst + i0) = __builtin_bit_cast(uint2, o0);
    *(uint2*)(dst + i0 + 4) = __builtin_bit_cast(uint2, o1);
  }
}

// ---------------------------------------------------------------------------
// RoPE: q_pe slices of bf16 qbuf in place; k_pe (bf16 ac) -> broadcast to Kb.
// ---------------------------------------------------------------------------
__global__ void rope_kernel(unsigned short* __restrict__ q, const unsigned short* __restrict__ ac,
                            unsigned short* __restrict__ Kb, const int* __restrict__ pos_ids) {
  const int s = blockIdx.x;
  const int j = threadIdx.x;  // 0..31
  const float t = (float)pos_ids[s];
  const float invf = powf(50000.0f, -(float)(2 * j) / 64.0f);
  const float ang = t * invf;
  const float c = cosf(ang), sn = sinf(ang);
  for (int h = 0; h < N_HEADS; ++h) {
    unsigned short* base = q + (size_t)s * (N_HEADS * QHD) + h * QHD + NOPE;
    const float x0 = u2f(base[2 * j]), x1 = u2f(base[2 * j + 1]);
    __syncthreads();
    base[j] = f2u(x0 * c - x1 * sn);
    base[32 + j] = f2u(x1 * c + x0 * sn);
    __syncthreads();
  }
  const unsigned short* kb = ac + (size_t)s * AC_W + 2048;
  const float kb0 = u2f(kb[2 * j]), kb1 = u2f(kb[2 * j + 1]);
  const unsigned short r0 = f2u(kb0 * c - kb1 * sn);
  const unsigned short r1 = f2u(kb1 * c + kb0 * sn);
#pragma unroll
  for (int h = 0; h < N_HEADS; ++h) {
    unsigned short* kd = Kb + ((size_t)h * S_LEN + s) * QHD + NOPE;
    kd[j] = r0;
    kd[32 + j] = r1;
  }
}

// ---------------------------------------------------------------------------
// Split-2 MFMA flash attention (R9 structure; bf16 partials). Unchanged.
// ---------------------------------------------------------------------------
__global__ __launch_bounds__(256, 4) void flash_attn(const unsigned short* __restrict__ Q,   // (S,3072) pre-scaled
                                                     const unsigned short* __restrict__ Kb,  // (H,S,192)
                                                     const unsigned short* __restrict__ Vt,  // (H,128,S) permuted
                                                     unsigned short* __restrict__ Pb,        // (S,2,16,128) bf16
                                                     float2* __restrict__ mlb) {             // (S,2,16) {m,l}
  __shared__ unsigned short Ks[2][32 * QHD];   // 2 x 12 KB
  __shared__ unsigned short Vs[2][VD * 32];    // 2 x  8 KB
  const int tid = threadIdx.x;
  const int wave = tid >> 6, lane = tid & 63;
  const int g = lane >> 4, col = lane & 15;
  const int lin = (int)blockIdx.x;                    // 0..1023
  const int h = ((lin & 7) << 1) | ((lin >> 3) & 1);  // XCD owns a head pair
  const int s = (lin >> 4) & 1;                       // k-split
  const int z = lin >> 5;                             // 0..31
  int t;                                              // balanced qblock mapping
  if (z < 8) t = 31 - z;
  else if (z < 16) t = z - 8;
  else if (z < 24) t = 39 - z;
  else t = z - 16;
  const int qw = t * 64 + wave * 16;
  const int qr = qw + col;

  bf16x8 qf[6];
  {
    const unsigned short* qrow = Q + (size_t)qr * (N_HEADS * QHD) + h * QHD + g * 8;
#pragma unroll
    for (int i = 0; i < 6; ++i) qf[i] = *(const bf16x8*)(qrow + i * 32);
  }

  const unsigned short* KbH = Kb + (size_t)h * S_LEN * QHD;
  const unsigned short* VtH = Vt + (size_t)h * VD * S_LEN;

  // staging source offsets (pre-swizzled slots; fixed across tiles)
  int eK[3], eV[2];
#pragma unroll
  for (int i = 0; i < 3; ++i) {                 // 768 K chunks of 16B
    const int c = i * 256 + tid;
    const int r = c / 24, sl = c - r * 24;
    eK[i] = r * QHD + (((sl & 24) | ((sl & 7) ^ (r & 7)))) * 8;
  }
#pragma unroll
  for (int i = 0; i < 2; ++i) {                 // 512 V chunks of 16B
    const int c = i * 256 + tid;
    const int d = c >> 2, sl = c & 3;
    eV[i] = d * S_LEN + ((sl ^ (d & 3))) * 8;
  }

  f32x4 o[8];
#pragma unroll
  for (int i = 0; i < 8; ++i) o[i] = (f32x4){0.f, 0.f, 0.f, 0.f};
  float m = -1e30f, l = 0.f;

  const int nT = t + 1;  // tiles j = 2*it + s

  // prologue: stage tile j=s into buffer 0
  {
    const unsigned short* kp = KbH + (size_t)s * 32 * QHD;
    const unsigned short* vp = VtH + s * 32;
#pragma unroll
    for (int i = 0; i < 3; ++i) gload_lds16(kp + eK[i], &Ks[0][(i * 256 + tid) * 8]);
#pragma unroll
    for (int i = 0; i < 2; ++i) gload_lds16(vp + eV[i], &Vs[0][(i * 256 + tid) * 8]);
  }

  int xK[6];
#pragma unroll
  for (int i = 0; i < 6; ++i) xK[i] = ((4 * i + g) ^ (col & 7)) * 8;
  const int rbK = col * QHD;
  const int xV = (g ^ (col & 3)) * 8;
  const int rbV = col * 32;

  for (int it = 0; it < nT; ++it) {
    __syncthreads();
    if (it + 1 < nT) {
      const int jn = 2 * (it + 1) + s;
      const unsigned short* kp = KbH + (size_t)jn * 32 * QHD;
      const unsigned short* vp = VtH + jn * 32;
      const int b = (it + 1) & 1;
#pragma unroll
      for (int i = 0; i < 3; ++i) gload_lds16(kp + eK[i], &Ks[b][(i * 256 + tid) * 8]);
#pragma unroll
      for (int i = 0; i < 2; ++i) gload_lds16(vp + eV[i], &Vs[b][(i * 256 + tid) * 8]);
    }
    const int k0 = 32 * (2 * it + s);
    if (k0 <= qw + 15) {
      const unsigned short* Ksc = Ks[it & 1];
      const unsigned short* Vsc = Vs[it & 1];

      f32x4 c0 = (f32x4){0.f, 0.f, 0.f, 0.f}, c1 = (f32x4){0.f, 0.f, 0.f, 0.f};
      __builtin_amdgcn_s_setprio(1);
#pragma unroll
      for (int dt = 0; dt < 6; ++dt) {
        const bf16x8 a0 = *(const bf16x8*)(Ksc + rbK + xK[dt]);
        const bf16x8 a1 = *(const bf16x8*)(Ksc + rbK + 16 * QHD + xK[dt]);
        c0 = __builtin_amdgcn_mfma_f32_16x16x32_bf16(a0, qf[dt], c0, 0, 0, 0);
        c1 = __builtin_amdgcn_mfma_f32_16x16x32_bf16(a1, qf[dt], c1, 0, 0, 0);
      }
      __builtin_amdgcn_s_setprio(0);

      // causal mask only on diagonal tiles (k = k0 + 16*frag + 4g + r)
      if (k0 + 31 > qw) {
#pragma unroll
        for (int r = 0; r < 4; ++r) {
          const int kk = k0 + 4 * g + r;
          if (kk > qr) c0[r] = -1e30f;
          if (kk + 16 > qr) c1[r] = -1e30f;
        }
      }
      float bm = fmaxf(fmaxf(fmaxf(c0[0], c0[1]), fmaxf(c0[2], c0[3])),
                       fmaxf(fmaxf(c1[0], c1[1]), fmaxf(c1[2], c1[3])));
      bm = fmaxf(bm, __shfl_xor(bm, 16));
      bm = fmaxf(bm, __shfl_xor(bm, 32));
      const bool skip = __all(bm <= m + 8.f);   // defer-max: p bounded by 2^8
      const float mn = skip ? m : fmaxf(m, bm);
      float ps = 0.f;
      bf16x8 pb;
#pragma unroll
      for (int r = 0; r < 4; ++r) {
        const float p0 = exp2f(c0[r] - mn);
        const float p1 = exp2f(c1[r] - mn);
        ps += p0 + p1;
        pb[r] = (short)f2u_fast(p0);
        pb[4 + r] = (short)f2u_fast(p1);
      }
      ps += __shfl_xor(ps, 16);
      ps += __shfl_xor(ps, 32);
      if (skip) {
        l += ps;
      } else {
        const float corr = exp2f(m - mn);
        l = l * corr + ps;
        m = mn;
#pragma unroll
        for (int i = 0; i < 8; ++i) {
          o[i][0] *= corr; o[i][1] *= corr; o[i][2] *= corr; o[i][3] *= corr;
        }
      }
      __builtin_amdgcn_s_setprio(1);
#pragma unroll
      for (int db = 0; db < 8; ++db) {
        const bf16x8 va = *(const bf16x8*)(Vsc + db * 512 + rbV + xV);
        o[db] = __builtin_amdgcn_mfma_f32_16x16x32_bf16(va, pb, o[db], 0, 0, 0);
      }
      __builtin_amdgcn_s_setprio(0);
    }
  }

  // epilogue: bf16 unnormalized partials + (m,l)
  unsigned short* pr = Pb + (((size_t)qr * 2 + s) * N_HEADS + h) * VD;
#pragma unroll
  for (int db = 0; db < 8; ++db) {
    u16x4 w4;
#pragma unroll
    for (int r = 0; r < 4; ++r) w4[r] = f2u(o[db][r]);
    *(uint2*)(pr + db * 16 + 4 * g) = __builtin_bit_cast(uint2, w4);
  }
  if (g == 0) mlb[((size_t)qr * 2 + s) * N_HEADS + h] = make_float2(m, l);
}

// ---------------------------------------------------------------------------
// Merge the two k-splits: out = (w0*P0 + w1*P1) / (w0*l0 + w1*l1), bf16.
// ---------------------------------------------------------------------------
__global__ __launch_bounds__(256) void combine2(const unsigned short* __restrict__ Pb,
                                                const float2* __restrict__ mlb,
                                                unsigned short* __restrict__ outb) {
  const int idx = blockIdx.x * 256 + threadIdx.x;  // exactly 524288
  const int d8 = idx & 15, hq = idx >> 4;
  const int h = hq & 15, q = hq >> 4;
  const float2 a = mlb[((size_t)q * 2 + 0) * N_HEADS + h];
  const float2 b = mlb[((size_t)q * 2 + 1) * N_HEADS + h];
  const float M = fmaxf(a.x, b.x);
  float wA = exp2f(a.x - M), wB = exp2f(b.x - M);
  const float inv = 1.f / (wA * a.y + wB * b.y);
  wA *= inv; wB *= inv;
  const bf16x8 v0 = *(const bf16x8*)(Pb + (((size_t)q * 2 + 0) * N_HEADS + h) * VD + d8 * 8);
  const bf16x8 v1 = *(const bf16x8*)(Pb + (((size_t)q * 2 + 1) * N_HEADS + h) * VD + d8 * 8);
  u16x4 o0, o1;
#pragma unroll
  for (int e = 0; e < 4; ++e) {
    o0[e] = f2u(u2f((unsigned short)v0[e]) * wA + u2f((unsigned short)v1[e]) * wB);
    o1[e] = f2u(u2f((unsigned short)v0[4 + e]) * wA + u2f((unsigned short)v1[4 + e]) * wB);
  }
  unsigned short* dst = outb + ((size_t)q * N_HEADS + h) * VD + d8 * 8;
  *(uint2*)(dst) = __builtin_bit_cast(uint2, o0);
  *(uint2*)(dst + 4) = __builtin_bit_cast(uint2, o1);
}

// ---------------------------------------------------------------------------
extern "C" void kernel_launch(void* const* d_in, const int* in_sizes, int n_in,
                              void* d_out, int out_size, void* d_ws, size_t ws_size,
                              hipStream_t stream) {
  const float* hidden    = (const float*)d_in[0];
  const int*   pos       = (const int*)d_in[1];
  const float* q_a_w     = (const float*)d_in[2];
  const float* q_a_ln_w  = (const float*)d_in[3];
  const float* q_b_w     = (const float*)d_in[4];
  const float* kv_a_w    = (const float*)d_in[5];
  const float* kv_a_ln_w = (const float*)d_in[6];
  const float* kv_b_w    = (const float*)d_in[7];
  const float* o_w       = (const float*)d_in[8];
  float* out = (float*)d_out;
  (void)in_sizes; (void)n_in; (void)out_size; (void)ws_size;

  // workspace layout (bytes); total ~94 MB
  char* base = (char*)d_ws;
  unsigned short* qbuf  = (unsigned short*)(base);              // S*3072 bf16  12.58MB
  unsigned short* Pbuf  = (unsigned short*)(base + 12582912);   // S*2*16*128 bf16 = 16.78MB
  unsigned short* acb   = (unsigned short*)(base + 29360128);   // S*2112 bf16   8.65MB
  unsigned short* qan   = (unsigned short*)(base + 46661632);   // S*1536 bf16   6.29MB
  float2*         mlb   = (float2*)(base + 46661632);           //   overlay: S*2*16 float2 (qan dead by flash)
  unsigned short* ckvn  = (unsigned short*)(base + 52953088);   // S*512 bf16    2.10MB
  unsigned short* Hb    = (unsigned short*)(base + 55050240);   // S*2048 bf16   8.39MB
  unsigned short* Vt    = (unsigned short*)(base + 55050240);   //   overlay (Hb dead after a-proj)
  unsigned short* wbuf  = (unsigned short*)(base + 63438848);   // 4.72M bf16    9.44MB
  unsigned short* attnb = (unsigned short*)(base + 72876032);   // S*2048 bf16   8.39MB
  unsigned short* kvbw  = (unsigned short*)(base + 72876032);   //   overlay: kv_b bf16 (dead before combine2)
  unsigned short* Kb    = (unsigned short*)(base + 81264640);   // 16*S*192 bf16 12.58MB

  const dim3 b256(256);
  // 192^-0.5 * log2(e): scores come out of QK^T directly in log2 domain
  const float qscale = 0.07216878364870323f * 1.4426950408889634f;

  // stage-1 conversions: hidden -> Hb, [q_a_w;kv_a_w] -> wbuf
  conv_stage1<<<2048, b256, 0, stream>>>(hidden, q_a_w, kv_a_w, Hb, wbuf);

  // fused a-proj: C = acb bf16 (S x 2112)
  gemm_mfma<1><<<dim3(AC_W / 64, S_LEN / 128), b256, 0, stream>>>(Hb, wbuf, acb, AC_W, D_MODEL);

  // fused double rmsnorm (q_a and kv slices), bf16 in
  rmsnorm2_kernel<<<dim3(S_LEN, 2), b256, 0, stream>>>(acb, q_a_ln_w, kv_a_ln_w, qan, ckvn);

  // stage-2 conversions: qscale*q_b_w -> wbuf, kv_b_w -> kvbw
  conv_stage2<<<2048, b256, 0, stream>>>(q_b_w, kv_b_w, wbuf, kvbw, qscale);

  // merged q_b + kv_b GEMMs (one launch, 1792 blocks; long q_b blocks first)
  gemm_qkv<<<dim3(1792), b256, 0, stream>>>(qan, wbuf, qbuf, ckvn, kvbw, Kb, Vt);

  // rope: qbuf q_pe in place; k_pe (bf16) -> Kb cols 128..192 (all heads)
  rope_kernel<<<S_LEN, 32, 0, stream>>>(qbuf, acb, Kb, pos);

  // split-2 flash (bf16 partials; ml over qan — both dead) + combine
  flash_attn<<<dim3(1024), b256, 0, stream>>>(qbuf, Kb, Vt, Pbuf, mlb);
  combine2<<<2048, b256, 0, stream>>>(Pbuf, mlb, attnb);

  // out = attnb @ o_w^T
  conv_bf16<<<2048, b256, 0, stream>>>(o_w, wbuf, (D_MODEL * N_HEADS * VD) / 4, 1.f);
  gemm_mfma<0><<<dim3(D_MODEL / 64, S_LEN / 128), b256, 0, stream>>>(attnb, wbuf, out, D_MODEL, N_HEADS * VD);
}

// Round 15
// 182.320 us; speedup vs baseline: 1.2024x; 1.0382x over previous
//
#include <hip/hip_runtime.h>
#include <hip/hip_bf16.h>
#include <cmath>

#define S_LEN 2048
#define D_MODEL 2048
#define N_HEADS 16
#define Q_LORA 1536
#define KV_LORA 512
#define NOPE 128
#define ROPE_D 64
#define VD 128
#define QHD 192
#define AC_W 2112  // fused a-proj output width: 1536 q_a + 576 ckv

typedef __attribute__((ext_vector_type(8))) short bf16x8;
typedef __attribute__((ext_vector_type(4))) float f32x4;
typedef __attribute__((ext_vector_type(4))) unsigned short u16x4;

static __device__ __forceinline__ unsigned short f2u(float x) {
  union { float f; unsigned u; } v; v.f = x;
  unsigned r = v.u + 0x7fffu + ((v.u >> 16) & 1u);  // RNE
  return (unsigned short)(r >> 16);
}
static __device__ __forceinline__ unsigned short f2u_fast(float x) {  // round-half-up, x>=0
  union { float f; unsigned u; } v; v.f = x;
  return (unsigned short)((v.u + 0x8000u) >> 16);
}
static __device__ __forceinline__ float u2f(unsigned short x) {
  union { unsigned u; float f; } v; v.u = ((unsigned)x) << 16;
  return v.f;
}

#define AS1 __attribute__((address_space(1)))
#define AS3 __attribute__((address_space(3)))
static __device__ __forceinline__ void gload_lds16(const unsigned short* g, unsigned short* l) {
  __builtin_amdgcn_global_load_lds((const AS1 unsigned int*)g, (AS3 unsigned int*)l, 16, 0, 0);
}

// stage-1 conversions in one launch: hidden -> Hb; [q_a_w ; kv_a_w] -> wbuf
__global__ __launch_bounds__(256) void conv_stage1(const float* __restrict__ hidden,
                                                   const float* __restrict__ qaw,
                                                   const float* __restrict__ kvaw,
                                                   unsigned short* __restrict__ Hb,
                                                   unsigned short* __restrict__ wbuf) {
  const int nH = (S_LEN * D_MODEL) / 4;
  const int nQ = (Q_LORA * D_MODEL) / 4;
  const int nT = nH + nQ + ((KV_LORA + ROPE_D) * D_MODEL) / 4;
  for (int i = blockIdx.x * 256 + threadIdx.x; i < nT; i += gridDim.x * 256) {
    float4 v;
    unsigned short* dst;
    int o;
    if (i < nH) {
      v = ((const float4*)hidden)[i]; dst = Hb; o = i;
    } else {
      o = i - nH;
      v = (o < nQ) ? ((const float4*)qaw)[o] : ((const float4*)kvaw)[o - nQ];
      dst = wbuf;
    }
    u16x4 u;
    u[0] = f2u(v.x); u[1] = f2u(v.y); u[2] = f2u(v.z); u[3] = f2u(v.w);
    ((u16x4*)dst)[o] = u;
  }
}

// stage-2 conversions in one launch: qscale*q_b_w -> wbuf; kv_b_w -> kvbw
__global__ __launch_bounds__(256) void conv_stage2(const float* __restrict__ qbw,
                                                   const float* __restrict__ kvbsrc,
                                                   unsigned short* __restrict__ wbuf,
                                                   unsigned short* __restrict__ kvbw,
                                                   float qscale) {
  const int nQB = (N_HEADS * QHD * Q_LORA) / 4;
  const int nT = nQB + (N_HEADS * 256 * KV_LORA) / 4;
  for (int i = blockIdx.x * 256 + threadIdx.x; i < nT; i += gridDim.x * 256) {
    u16x4 u;
    if (i < nQB) {
      const float4 v = ((const float4*)qbw)[i];
      u[0] = f2u(v.x * qscale); u[1] = f2u(v.y * qscale);
      u[2] = f2u(v.z * qscale); u[3] = f2u(v.w * qscale);
      ((u16x4*)wbuf)[i] = u;
    } else {
      const int o = i - nQB;
      const float4 v = ((const float4*)kvbsrc)[o];
      u[0] = f2u(v.x); u[1] = f2u(v.y); u[2] = f2u(v.z); u[3] = f2u(v.w);
      ((u16x4*)kvbw)[o] = u;
    }
  }
}

// ---------------------------------------------------------------------------
// bf16 MFMA GEMM: C[M,N] = A[M,K] @ W[N,K]^T. 128x64 tile, BK=64, 4 waves
// (each 64x32 output), double-buffered LDS (48 KB), one barrier per 64-k
// step, XOR-swizzled (pre-swizzled global source + same XOR on ds_read).
// MODE 0: f32 C. MODE 1: bf16 C.
// ---------------------------------------------------------------------------
template <int MODE>
__global__ __launch_bounds__(256) void gemm_mfma(const unsigned short* __restrict__ A,
                                                 const unsigned short* __restrict__ W,
                                                 void* __restrict__ Cv,
                                                 int N, int K) {
  __shared__ unsigned short As[2][8192];  // 128 x 64 bf16
  __shared__ unsigned short Ws[2][4096];  //  64 x 64 bf16
  const int tid = threadIdx.x;
  const int wave = tid >> 6, lane = tid & 63;
  const int col16 = lane & 15, g = lane >> 4;
  const int arow = blockIdx.y * 128, wrow = blockIdx.x * 64;
  const int wm = (wave >> 1) * 64, wn = (wave & 1) * 32;

  const unsigned short* gA[4];
  const unsigned short* gW[2];
  int dA[4], dW[2];
#pragma unroll
  for (int i = 0; i < 4; ++i) {
    const int c = i * 256 + tid;
    const int r = c >> 3, sl = c & 7;
    gA[i] = A + (size_t)(arow + r) * K + (sl ^ (r & 7)) * 8;
    dA[i] = c * 8;
  }
#pragma unroll
  for (int i = 0; i < 2; ++i) {
    const int c = i * 256 + tid;
    const int r = c >> 3, sl = c & 7;
    gW[i] = W + (size_t)(wrow + r) * K + (sl ^ (r & 7)) * 8;
    dW[i] = c * 8;
  }

  f32x4 acc[4][2];
#pragma unroll
  for (int i = 0; i < 4; ++i)
#pragma unroll
    for (int j = 0; j < 2; ++j) acc[i][j] = (f32x4){0.f, 0.f, 0.f, 0.f};

#pragma unroll
  for (int i = 0; i < 4; ++i) gload_lds16(gA[i], &As[0][dA[i]]);
#pragma unroll
  for (int i = 0; i < 2; ++i) gload_lds16(gW[i], &Ws[0][dW[i]]);

  int cur = 0;
  for (int k0 = 0; k0 < K; k0 += 64) {
    __syncthreads();
    if (k0 + 64 < K) {
      const int b = cur ^ 1, kk = k0 + 64;
#pragma unroll
      for (int i = 0; i < 4; ++i) gload_lds16(gA[i] + kk, &As[b][dA[i]]);
#pragma unroll
      for (int i = 0; i < 2; ++i) gload_lds16(gW[i] + kk, &Ws[b][dW[i]]);
    }
#pragma unroll
    for (int kh = 0; kh < 2; ++kh) {
      bf16x8 af[4], bfr[2];
#pragma unroll
      for (int i = 0; i < 4; ++i) {
        const int row = wm + i * 16 + col16;
        af[i] = *(const bf16x8*)(&As[cur][row * 64 + (((kh * 4 + g) ^ (row & 7)) * 8)]);
      }
#pragma unroll
      for (int j = 0; j < 2; ++j) {
        const int row = wn + j * 16 + col16;
        bfr[j] = *(const bf16x8*)(&Ws[cur][row * 64 + (((kh * 4 + g) ^ (row & 7)) * 8)]);
      }
#pragma unroll
      for (int i = 0; i < 4; ++i)
#pragma unroll
        for (int j = 0; j < 2; ++j)
          acc[i][j] = __builtin_amdgcn_mfma_f32_16x16x32_bf16(af[i], bfr[j], acc[i][j], 0, 0, 0);
    }
    cur ^= 1;
  }

#pragma unroll
  for (int i = 0; i < 4; ++i)
#pragma unroll
    for (int j = 0; j < 2; ++j) {
      const int col = wrow + wn + j * 16 + col16;
      const int row0 = arow + wm + i * 16 + g * 4;
#pragma unroll
      for (int r = 0; r < 4; ++r) {
        if constexpr (MODE == 0)
          ((float*)Cv)[(size_t)(row0 + r) * N + col] = acc[i][j][r];
        else
          ((unsigned short*)Cv)[(size_t)(row0 + r) * N + col] = f2u(acc[i][j][r]);
      }
    }
}

// ---------------------------------------------------------------------------
// Merged q_b + kv_b GEMM (one launch, 1792 blocks). bid<768: q_b; else kv_b
// (k_nope -> Kb; values -> Vt with PV permutation fused).
// ---------------------------------------------------------------------------
__global__ __launch_bounds__(256) void gemm_qkv(const unsigned short* __restrict__ qan,
                                                const unsigned short* __restrict__ wq,
                                                unsigned short* __restrict__ qbuf,
                                                const unsigned short* __restrict__ ckvn,
                                                const unsigned short* __restrict__ wkv,
                                                unsigned short* __restrict__ Kb,
                                                unsigned short* __restrict__ Vt) {
  __shared__ unsigned short As[2][8192];
  __shared__ unsigned short Ws[2][4096];
  const int tid = threadIdx.x;
  const int wave = tid >> 6, lane = tid & 63;
  const int col16 = lane & 15, g = lane >> 4;
  const int bid = (int)blockIdx.x;
  const bool isQ = bid < 768;
  int bx, by;
  if (isQ) { bx = bid % 48; by = bid / 48; }
  else { const int r = bid - 768; bx = r & 63; by = r >> 6; }
  const int K = isQ ? Q_LORA : KV_LORA;
  const unsigned short* A = isQ ? qan : ckvn;
  const unsigned short* W = isQ ? wq : wkv;
  const int arow = by * 128, wrow = bx * 64;
  const int wm = (wave >> 1) * 64, wn = (wave & 1) * 32;

  const unsigned short* gA[4];
  const unsigned short* gW[2];
  int dA[4], dW[2];
#pragma unroll
  for (int i = 0; i < 4; ++i) {
    const int c = i * 256 + tid;
    const int r = c >> 3, sl = c & 7;
    gA[i] = A + (size_t)(arow + r) * K + (sl ^ (r & 7)) * 8;
    dA[i] = c * 8;
  }
#pragma unroll
  for (int i = 0; i < 2; ++i) {
    const int c = i * 256 + tid;
    const int r = c >> 3, sl = c & 7;
    gW[i] = W + (size_t)(wrow + r) * K + (sl ^ (r & 7)) * 8;
    dW[i] = c * 8;
  }

  f32x4 acc[4][2];
#pragma unroll
  for (int i = 0; i < 4; ++i)
#pragma unroll
    for (int j = 0; j < 2; ++j) acc[i][j] = (f32x4){0.f, 0.f, 0.f, 0.f};

#pragma unroll
  for (int i = 0; i < 4; ++i) gload_lds16(gA[i], &As[0][dA[i]]);
#pragma unroll
  for (int i = 0; i < 2; ++i) gload_lds16(gW[i], &Ws[0][dW[i]]);

  int cur = 0;
  for (int k0 = 0; k0 < K; k0 += 64) {
    __syncthreads();
    if (k0 + 64 < K) {
      const int b = cur ^ 1, kk = k0 + 64;
#pragma unroll
      for (int i = 0; i < 4; ++i) gload_lds16(gA[i] + kk, &As[b][dA[i]]);
#pragma unroll
      for (int i = 0; i < 2; ++i) gload_lds16(gW[i] + kk, &Ws[b][dW[i]]);
    }
#pragma unroll
    for (int kh = 0; kh < 2; ++kh) {
      bf16x8 af[4], bfr[2];
#pragma unroll
      for (int i = 0; i < 4; ++i) {
        const int row = wm + i * 16 + col16;
        af[i] = *(const bf16x8*)(&As[cur][row * 64 + (((kh * 4 + g) ^ (row & 7)) * 8)]);
      }
#pragma unroll
      for (int j = 0; j < 2; ++j) {
        const int row = wn + j * 16 + col16;
        bfr[j] = *(const bf16x8*)(&Ws[cur][row * 64 + (((kh * 4 + g) ^ (row & 7)) * 8)]);
      }
#pragma unroll
      for (int i = 0; i < 4; ++i)
#pragma unroll
        for (int j = 0; j < 2; ++j)
          acc[i][j] = __builtin_amdgcn_mfma_f32_16x16x32_bf16(af[i], bfr[j], acc[i][j], 0, 0, 0);
    }
    cur ^= 1;
  }

#pragma unroll
  for (int i = 0; i < 4; ++i)
#pragma unroll
    for (int j = 0; j < 2; ++j) {
      const int col = wrow + wn + j * 16 + col16;
      const int row0 = arow + wm + i * 16 + g * 4;
      if (isQ) {
#pragma unroll
        for (int r = 0; r < 4; ++r)
          qbuf[(size_t)(row0 + r) * (N_HEADS * QHD) + col] = f2u(acc[i][j][r]);
      } else {
        const int hh = col >> 8, d = col & 255;
        if (d < NOPE) {
#pragma unroll
          for (int r = 0; r < 4; ++r)
            Kb[((size_t)hh * S_LEN + row0 + r) * QHD + d] = f2u(acc[i][j][r]);
        } else {
          // fused build_vt: Vt(h, d-128, (row0&~31) + perm(row0&31) + r)
          const int dv = d - NOPE;
          const int p0 = ((row0 & 15) >> 2) * 8 + ((row0 >> 4) & 1) * 4;
          u16x4 w4;
#pragma unroll
          for (int r = 0; r < 4; ++r) w4[r] = f2u(acc[i][j][r]);
          *(uint2*)(Vt + ((size_t)hh * VD + dv) * S_LEN + (row0 & ~31) + p0) =
              __builtin_bit_cast(uint2, w4);
        }
      }
    }
}

// ---------------------------------------------------------------------------
// Fused RMSNorm, bf16 input (ac bf16, ld 2112) -> bf16 out, vectorized x8.
// blockIdx.y = 0 -> q_a slice (1536), 1 -> kv slice (512).
// ---------------------------------------------------------------------------
__global__ __launch_bounds__(256) void rmsnorm2_kernel(const unsigned short* __restrict__ ac,
                                                       const float* __restrict__ wq,
                                                       const float* __restrict__ wkv,
                                                       unsigned short* __restrict__ qan,
                                                       unsigned short* __restrict__ ckvn) {
  const int row = blockIdx.x;
  const bool kv = blockIdx.y != 0;
  const unsigned short* x = ac + (size_t)row * AC_W + (kv ? Q_LORA : 0);
  const float* w = kv ? wkv : wq;
  unsigned short* dst = kv ? (ckvn + (size_t)row * KV_LORA) : (qan + (size_t)row * Q_LORA);
  const int dim = kv ? KV_LORA : Q_LORA;
  float ss = 0.f;
  for (int i0 = threadIdx.x * 8; i0 < dim; i0 += 2048) {
    const bf16x8 v = *(const bf16x8*)(x + i0);
#pragma unroll
    for (int e = 0; e < 8; ++e) {
      const float f = u2f((unsigned short)v[e]);
      ss += f * f;
    }
  }
#pragma unroll
  for (int off = 32; off; off >>= 1) ss += __shfl_xor(ss, off);
  __shared__ float red[4];
  const int wv = threadIdx.x >> 6, ln = threadIdx.x & 63;
  if (ln == 0) red[wv] = ss;
  __syncthreads();
  const float tot = red[0] + red[1] + red[2] + red[3];
  const float scale = rsqrtf(tot / (float)dim + 1e-6f);
  for (int i0 = threadIdx.x * 8; i0 < dim; i0 += 2048) {
    const bf16x8 v = *(const bf16x8*)(x + i0);
    u16x4 o0, o1;
#pragma unroll
    for (int e = 0; e < 4; ++e) {
      o0[e] = f2u(w[i0 + e] * (u2f((unsigned short)v[e]) * scale));
      o1[e] = f2u(w[i0 + 4 + e] * (u2f((unsigned short)v[4 + e]) * scale));
    }
    *(uint2*)(dst + i0) = __builtin_bit_cast(uint2, o0);
    *(uint2*)(dst + i0 + 4) = __builtin_bit_cast(uint2, o1);
  }
}

// ---------------------------------------------------------------------------
// RoPE, wave-parallel: 256 threads = 8 rows (one per 32-lane group), no
// barriers needed (in-wave lockstep orders loads before stores).
// ---------------------------------------------------------------------------
__global__ __launch_bounds__(256) void rope_kernel(unsigned short* __restrict__ q,
                                                   const unsigned short* __restrict__ ac,
                                                   unsigned short* __restrict__ Kb,
                                                   const int* __restrict__ pos_ids) {
  const int s = blockIdx.x * 8 + (threadIdx.x >> 5);
  const int j = threadIdx.x & 31;
  const float t = (float)pos_ids[s];
  const float invf = powf(50000.0f, -(float)(2 * j) / 64.0f);
  const float ang = t * invf;
  const float c = cosf(ang), sn = sinf(ang);
#pragma unroll
  for (int h = 0; h < N_HEADS; ++h) {
    unsigned short* base = q + (size_t)s * (N_HEADS * QHD) + h * QHD + NOPE;
    const float x0 = u2f(base[2 * j]), x1 = u2f(base[2 * j + 1]);
    base[j] = f2u(x0 * c - x1 * sn);
    base[32 + j] = f2u(x1 * c + x0 * sn);
  }
  const unsigned short* kb = ac + (size_t)s * AC_W + 2048;
  const float kb0 = u2f(kb[2 * j]), kb1 = u2f(kb[2 * j + 1]);
  const unsigned short r0 = f2u(kb0 * c - kb1 * sn);
  const unsigned short r1 = f2u(kb1 * c + kb0 * sn);
#pragma unroll
  for (int h = 0; h < N_HEADS; ++h) {
    unsigned short* kd = Kb + ((size_t)h * S_LEN + s) * QHD + NOPE;
    kd[j] = r0;
    kd[32 + j] = r1;
  }
}

// ---------------------------------------------------------------------------
// Split-2 MFMA flash attention (R9 structure; bf16 partials). V LDS re-
// geometried to 64 row-pairs x 128B with slot pos = ((d&1)*4+sl)^((d>>1)&7):
// per quarter-wave each 16B bank-quad is hit by exactly 2 lanes (2-way =
// free) vs 4-way before. Inverse permutation applied on the global source
// (linear gload_lds dest), forward on the read — canonical data preserved.
// ---------------------------------------------------------------------------
__global__ __launch_bounds__(256, 4) void flash_attn(const unsigned short* __restrict__ Q,   // (S,3072) pre-scaled
                                                     const unsigned short* __restrict__ Kb,  // (H,S,192)
                                                     const unsigned short* __restrict__ Vt,  // (H,128,S) permuted
                                                     unsigned short* __restrict__ Pb,        // (S,2,16,128) bf16
                                                     float2* __restrict__ mlb) {             // (S,2,16) {m,l}
  __shared__ unsigned short Ks[2][32 * QHD];   // 2 x 12 KB
  __shared__ unsigned short Vs[2][VD * 32];    // 2 x  8 KB
  const int tid = threadIdx.x;
  const int wave = tid >> 6, lane = tid & 63;
  const int g = lane >> 4, col = lane & 15;
  const int lin = (int)blockIdx.x;                    // 0..1023
  const int h = ((lin & 7) << 1) | ((lin >> 3) & 1);  // XCD owns a head pair
  const int s = (lin >> 4) & 1;                       // k-split
  const int z = lin >> 5;                             // 0..31
  int t;                                              // balanced qblock mapping
  if (z < 8) t = 31 - z;
  else if (z < 16) t = z - 8;
  else if (z < 24) t = 39 - z;
  else t = z - 16;
  const int qw = t * 64 + wave * 16;
  const int qr = qw + col;

  bf16x8 qf[6];
  {
    const unsigned short* qrow = Q + (size_t)qr * (N_HEADS * QHD) + h * QHD + g * 8;
#pragma unroll
    for (int i = 0; i < 6; ++i) qf[i] = *(const bf16x8*)(qrow + i * 32);
  }

  const unsigned short* KbH = Kb + (size_t)h * S_LEN * QHD;
  const unsigned short* VtH = Vt + (size_t)h * VD * S_LEN;

  // staging source offsets (pre-swizzled slots; fixed across tiles)
  int eK[3], eV[2];
#pragma unroll
  for (int i = 0; i < 3; ++i) {                 // 768 K chunks of 16B
    const int c = i * 256 + tid;
    const int r = c / 24, sl = c - r * 24;
    eK[i] = r * QHD + (((sl & 24) | ((sl & 7) ^ (r & 7)))) * 8;
  }
#pragma unroll
  for (int i = 0; i < 2; ++i) {                 // 512 V chunks of 16B
    const int L = i * 256 + tid;                // LDS linear chunk
    const int r = L >> 3, p = L & 7;
    const int px = p ^ (r & 7);
    const int d = 2 * r + (px >> 2), sl = px & 3;
    eV[i] = d * S_LEN + sl * 8;
  }

  f32x4 o[8];
#pragma unroll
  for (int i = 0; i < 8; ++i) o[i] = (f32x4){0.f, 0.f, 0.f, 0.f};
  float m = -1e30f, l = 0.f;

  const int nT = t + 1;  // tiles j = 2*it + s

  // prologue: stage tile j=s into buffer 0
  {
    const unsigned short* kp = KbH + (size_t)s * 32 * QHD;
    const unsigned short* vp = VtH + s * 32;
#pragma unroll
    for (int i = 0; i < 3; ++i) gload_lds16(kp + eK[i], &Ks[0][(i * 256 + tid) * 8]);
#pragma unroll
    for (int i = 0; i < 2; ++i) gload_lds16(vp + eV[i], &Vs[0][(i * 256 + tid) * 8]);
  }

  int xK[6];
#pragma unroll
  for (int i = 0; i < 6; ++i) xK[i] = ((4 * i + g) ^ (col & 7)) * 8;
  const int rbK = col * QHD;
  // V read: lane needs (d = db*16+col, chunk g): elem = db*512 + vlane
  const int vlane = (col >> 1) * 64 + ((((col & 1) << 2) + g) ^ (col >> 1)) * 8;

  for (int it = 0; it < nT; ++it) {
    __syncthreads();
    if (it + 1 < nT) {
      const int jn = 2 * (it + 1) + s;
      const unsigned short* kp = KbH + (size_t)jn * 32 * QHD;
      const unsigned short* vp = VtH + jn * 32;
      const int b = (it + 1) & 1;
#pragma unroll
      for (int i = 0; i < 3; ++i) gload_lds16(kp + eK[i], &Ks[b][(i * 256 + tid) * 8]);
#pragma unroll
      for (int i = 0; i < 2; ++i) gload_lds16(vp + eV[i], &Vs[b][(i * 256 + tid) * 8]);
    }
    const int k0 = 32 * (2 * it + s);
    if (k0 <= qw + 15) {
      const unsigned short* Ksc = Ks[it & 1];
      const unsigned short* Vsc = Vs[it & 1];

      f32x4 c0 = (f32x4){0.f, 0.f, 0.f, 0.f}, c1 = (f32x4){0.f, 0.f, 0.f, 0.f};
      __builtin_amdgcn_s_setprio(1);
#pragma unroll
      for (int dt = 0; dt < 6; ++dt) {
        const bf16x8 a0 = *(const bf16x8*)(Ksc + rbK + xK[dt]);
        const bf16x8 a1 = *(const bf16x8*)(Ksc + rbK + 16 * QHD + xK[dt]);
        c0 = __builtin_amdgcn_mfma_f32_16x16x32_bf16(a0, qf[dt], c0, 0, 0, 0);
        c1 = __builtin_amdgcn_mfma_f32_16x16x32_bf16(a1, qf[dt], c1, 0, 0, 0);
      }
      __builtin_amdgcn_s_setprio(0);

      // causal mask only on diagonal tiles (k = k0 + 16*frag + 4g + r)
      if (k0 + 31 > qw) {
#pragma unroll
        for (int r = 0; r < 4; ++r) {
          const int kk = k0 + 4 * g + r;
          if (kk > qr) c0[r] = -1e30f;
          if (kk + 16 > qr) c1[r] = -1e30f;
        }
      }
      float bm = fmaxf(fmaxf(fmaxf(c0[0], c0[1]), fmaxf(c0[2], c0[3])),
                       fmaxf(fmaxf(c1[0], c1[1]), fmaxf(c1[2], c1[3])));
      bm = fmaxf(bm, __shfl_xor(bm, 16));
      bm = fmaxf(bm, __shfl_xor(bm, 32));
      const bool skip = __all(bm <= m + 8.f);   // defer-max: p bounded by 2^8
      const float mn = skip ? m : fmaxf(m, bm);
      float ps = 0.f;
      bf16x8 pb;
#pragma unroll
      for (int r = 0; r < 4; ++r) {
        const float p0 = exp2f(c0[r] - mn);
        const float p1 = exp2f(c1[r] - mn);
        ps += p0 + p1;
        pb[r] = (short)f2u_fast(p0);
        pb[4 + r] = (short)f2u_fast(p1);
      }
      ps += __shfl_xor(ps, 16);
      ps += __shfl_xor(ps, 32);
      if (skip) {
        l += ps;
      } else {
        const float corr = exp2f(m - mn);
        l = l * corr + ps;
        m = mn;
#pragma unroll
        for (int i = 0; i < 8; ++i) {
          o[i][0] *= corr; o[i][1] *= corr; o[i][2] *= corr; o[i][3] *= corr;
        }
      }
      __builtin_amdgcn_s_setprio(1);
#pragma unroll
      for (int db = 0; db < 8; ++db) {
        const bf16x8 va = *(const bf16x8*)(Vsc + db * 512 + vlane);
        o[db] = __builtin_amdgcn_mfma_f32_16x16x32_bf16(va, pb, o[db], 0, 0, 0);
      }
      __builtin_amdgcn_s_setprio(0);
    }
  }

  // epilogue: bf16 unnormalized partials + (m,l)
  unsigned short* pr = Pb + (((size_t)qr * 2 + s) * N_HEADS + h) * VD;
#pragma unroll
  for (int db = 0; db < 8; ++db) {
    u16x4 w4;
#pragma unroll
    for (int r = 0; r < 4; ++r) w4[r] = f2u(o[db][r]);
    *(uint2*)(pr + db * 16 + 4 * g) = __builtin_bit_cast(uint2, w4);
  }
  if (g == 0) mlb[((size_t)qr * 2 + s) * N_HEADS + h] = make_float2(m, l);
}

// ---------------------------------------------------------------------------
// Merge the two k-splits + convert o_w to bf16 (both memory-bound, 1 launch).
// ---------------------------------------------------------------------------
__global__ __launch_bounds__(256) void combine2(const unsigned short* __restrict__ Pb,
                                                const float2* __restrict__ mlb,
                                                unsigned short* __restrict__ outb,
                                                const float* __restrict__ ow,
                                                unsigned short* __restrict__ owb) {
  const int nC = S_LEN * N_HEADS * VD / 8;           // 524288 combine items
  const int nT = nC + (D_MODEL * N_HEADS * VD) / 4;  // + 1048576 conv items
  for (int idx = blockIdx.x * 256 + threadIdx.x; idx < nT; idx += gridDim.x * 256) {
    if (idx < nC) {
      const int d8 = idx & 15, hq = idx >> 4;
      const int h = hq & 15, q = hq >> 4;
      const float2 a = mlb[((size_t)q * 2 + 0) * N_HEADS + h];
      const float2 b = mlb[((size_t)q * 2 + 1) * N_HEADS + h];
      const float M = fmaxf(a.x, b.x);
      float wA = exp2f(a.x - M), wB = exp2f(b.x - M);
      const float inv = 1.f / (wA * a.y + wB * b.y);
      wA *= inv; wB *= inv;
      const bf16x8 v0 = *(const bf16x8*)(Pb + (((size_t)q * 2 + 0) * N_HEADS + h) * VD + d8 * 8);
      const bf16x8 v1 = *(const bf16x8*)(Pb + (((size_t)q * 2 + 1) * N_HEADS + h) * VD + d8 * 8);
      u16x4 o0, o1;
#pragma unroll
      for (int e = 0; e < 4; ++e) {
        o0[e] = f2u(u2f((unsigned short)v0[e]) * wA + u2f((unsigned short)v1[e]) * wB);
        o1[e] = f2u(u2f((unsigned short)v0[4 + e]) * wA + u2f((unsigned short)v1[4 + e]) * wB);
      }
      unsigned short* dst = outb + ((size_t)q * N_HEADS + h) * VD + d8 * 8;
      *(uint2*)(dst) = __builtin_bit_cast(uint2, o0);
      *(uint2*)(dst + 4) = __builtin_bit_cast(uint2, o1);
    } else {
      const int i = idx - nC;
      const float4 v = ((const float4*)ow)[i];
      u16x4 u;
      u[0] = f2u(v.x); u[1] = f2u(v.y); u[2] = f2u(v.z); u[3] = f2u(v.w);
      ((u16x4*)owb)[i] = u;
    }
  }
}

// ---------------------------------------------------------------------------
extern "C" void kernel_launch(void* const* d_in, const int* in_sizes, int n_in,
                              void* d_out, int out_size, void* d_ws, size_t ws_size,
                              hipStream_t stream) {
  const float* hidden    = (const float*)d_in[0];
  const int*   pos       = (const int*)d_in[1];
  const float* q_a_w     = (const float*)d_in[2];
  const float* q_a_ln_w  = (const float*)d_in[3];
  const float* q_b_w     = (const float*)d_in[4];
  const float* kv_a_w    = (const float*)d_in[5];
  const float* kv_a_ln_w = (const float*)d_in[6];
  const float* kv_b_w    = (const float*)d_in[7];
  const float* o_w       = (const float*)d_in[8];
  float* out = (float*)d_out;
  (void)in_sizes; (void)n_in; (void)out_size; (void)ws_size;

  // workspace layout (bytes); total ~94 MB
  char* base = (char*)d_ws;
  unsigned short* qbuf  = (unsigned short*)(base);              // S*3072 bf16  12.58MB
  unsigned short* Pbuf  = (unsigned short*)(base + 12582912);   // S*2*16*128 bf16 = 16.78MB
  unsigned short* acb   = (unsigned short*)(base + 29360128);   // S*2112 bf16   8.65MB
  unsigned short* qan   = (unsigned short*)(base + 46661632);   // S*1536 bf16   6.29MB
  float2*         mlb   = (float2*)(base + 46661632);           //   overlay: S*2*16 float2 (qan dead by flash)
  unsigned short* ckvn  = (unsigned short*)(base + 52953088);   // S*512 bf16    2.10MB
  unsigned short* Hb    = (unsigned short*)(base + 55050240);   // S*2048 bf16   8.39MB
  unsigned short* Vt    = (unsigned short*)(base + 55050240);   //   overlay (Hb dead after a-proj)
  unsigned short* wbuf  = (unsigned short*)(base + 63438848);   // 4.72M bf16    9.44MB
  unsigned short* attnb = (unsigned short*)(base + 72876032);   // S*2048 bf16   8.39MB
  unsigned short* kvbw  = (unsigned short*)(base + 72876032);   //   overlay: kv_b bf16 (dead before combine2)
  unsigned short* Kb    = (unsigned short*)(base + 81264640);   // 16*S*192 bf16 12.58MB

  const dim3 b256(256);
  // 192^-0.5 * log2(e): scores come out of QK^T directly in log2 domain
  const float qscale = 0.07216878364870323f * 1.4426950408889634f;

  // stage-1 conversions: hidden -> Hb, [q_a_w;kv_a_w] -> wbuf
  conv_stage1<<<2048, b256, 0, stream>>>(hidden, q_a_w, kv_a_w, Hb, wbuf);

  // fused a-proj: C = acb bf16 (S x 2112)
  gemm_mfma<1><<<dim3(AC_W / 64, S_LEN / 128), b256, 0, stream>>>(Hb, wbuf, acb, AC_W, D_MODEL);

  // fused double rmsnorm (q_a and kv slices), bf16 in
  rmsnorm2_kernel<<<dim3(S_LEN, 2), b256, 0, stream>>>(acb, q_a_ln_w, kv_a_ln_w, qan, ckvn);

  // stage-2 conversions: qscale*q_b_w -> wbuf, kv_b_w -> kvbw
  conv_stage2<<<2048, b256, 0, stream>>>(q_b_w, kv_b_w, wbuf, kvbw, qscale);

  // merged q_b + kv_b GEMMs (one launch, 1792 blocks)
  gemm_qkv<<<dim3(1792), b256, 0, stream>>>(qan, wbuf, qbuf, ckvn, kvbw, Kb, Vt);

  // rope: qbuf q_pe in place; k_pe (bf16) -> Kb cols 128..192 (all heads)
  rope_kernel<<<S_LEN / 8, b256, 0, stream>>>(qbuf, acb, Kb, pos);

  // split-2 flash (bf16 partials; ml over qan — both dead)
  flash_attn<<<dim3(1024), b256, 0, stream>>>(qbuf, Kb, Vt, Pbuf, mlb);

  // combine splits + convert o_w (wbuf free after gemm_qkv)
  combine2<<<2048, b256, 0, stream>>>(Pbuf, mlb, attnb, o_w, wbuf);

  // out = attnb @ o_w^T
  gemm_mfma<0><<<dim3(D_MODEL / 64, S_LEN / 128), b256, 0, stream>>>(attnb, wbuf, out, D_MODEL, N_HEADS * VD);
}

// Round 16
// 180.852 us; speedup vs baseline: 1.2122x; 1.0081x over previous
//
#include <hip/hip_runtime.h>
#include <hip/hip_bf16.h>
#include <cmath>

#define S_LEN 2048
#define D_MODEL 2048
#define N_HEADS 16
#define Q_LORA 1536
#define KV_LORA 512
#define NOPE 128
#define ROPE_D 64
#define VD 128
#define QHD 192
#define AC_W 2112  // fused a-proj output width: 1536 q_a + 576 ckv

typedef __attribute__((ext_vector_type(8))) short bf16x8;
typedef __attribute__((ext_vector_type(4))) float f32x4;
typedef __attribute__((ext_vector_type(4))) unsigned short u16x4;

static __device__ __forceinline__ unsigned short f2u(float x) {
  union { float f; unsigned u; } v; v.f = x;
  unsigned r = v.u + 0x7fffu + ((v.u >> 16) & 1u);  // RNE
  return (unsigned short)(r >> 16);
}
static __device__ __forceinline__ unsigned short f2u_fast(float x) {  // round-half-up, x>=0
  union { float f; unsigned u; } v; v.f = x;
  return (unsigned short)((v.u + 0x8000u) >> 16);
}
static __device__ __forceinline__ float u2f(unsigned short x) {
  union { unsigned u; float f; } v; v.u = ((unsigned)x) << 16;
  return v.f;
}

#define AS1 __attribute__((address_space(1)))
#define AS3 __attribute__((address_space(3)))
static __device__ __forceinline__ void gload_lds16(const unsigned short* g, unsigned short* l) {
  __builtin_amdgcn_global_load_lds((const AS1 unsigned int*)g, (AS3 unsigned int*)l, 16, 0, 0);
}

// ---------------------------------------------------------------------------
// ALL input conversions in one launch (pure-input reads, no dependencies):
//   hidden -> Hb; [q_a_w;kv_a_w] -> wbuf; qscale*q_b_w -> qbwb; kv_b_w -> kvbwb
// ---------------------------------------------------------------------------
__global__ __launch_bounds__(256) void conv_all(const float* __restrict__ hidden,
                                                const float* __restrict__ qaw,
                                                const float* __restrict__ kvaw,
                                                const float* __restrict__ qbw,
                                                const float* __restrict__ kvbw,
                                                unsigned short* __restrict__ Hb,
                                                unsigned short* __restrict__ wbuf,
                                                unsigned short* __restrict__ qbwb,
                                                unsigned short* __restrict__ kvbwb,
                                                float qscale) {
  const int nH   = (S_LEN * D_MODEL) / 4;
  const int nQA  = (Q_LORA * D_MODEL) / 4;
  const int nKVA = ((KV_LORA + ROPE_D) * D_MODEL) / 4;
  const int nQB  = (N_HEADS * QHD * Q_LORA) / 4;
  const int nKVB = (N_HEADS * 256 * KV_LORA) / 4;
  const int e1 = nH, e2 = e1 + nQA + nKVA, e3 = e2 + nQB, e4 = e3 + nKVB;
  for (int i = blockIdx.x * 256 + threadIdx.x; i < e4; i += gridDim.x * 256) {
    float4 v;
    unsigned short* dst;
    int o;
    float sc = 1.f;
    if (i < e1) {
      o = i; v = ((const float4*)hidden)[o]; dst = Hb;
    } else if (i < e2) {
      o = i - e1;
      v = (o < nQA) ? ((const float4*)qaw)[o] : ((const float4*)kvaw)[o - nQA];
      dst = wbuf;
    } else if (i < e3) {
      o = i - e2; v = ((const float4*)qbw)[o]; dst = qbwb; sc = qscale;
    } else {
      o = i - e3; v = ((const float4*)kvbw)[o]; dst = kvbwb;
    }
    u16x4 u;
    u[0] = f2u(v.x * sc); u[1] = f2u(v.y * sc);
    u[2] = f2u(v.z * sc); u[3] = f2u(v.w * sc);
    ((u16x4*)dst)[o] = u;
  }
}

// ---------------------------------------------------------------------------
// bf16 MFMA GEMM: C[M,N] = A[M,K] @ W[N,K]^T. 128x64 tile, BK=64, 4 waves
// (each 64x32 output), double-buffered LDS (48 KB), one barrier per 64-k
// step, XOR-swizzled (pre-swizzled global source + same XOR on ds_read).
// MODE 0: f32 C. MODE 1: bf16 C.
// ---------------------------------------------------------------------------
template <int MODE>
__global__ __launch_bounds__(256) void gemm_mfma(const unsigned short* __restrict__ A,
                                                 const unsigned short* __restrict__ W,
                                                 void* __restrict__ Cv,
                                                 int N, int K) {
  __shared__ unsigned short As[2][8192];  // 128 x 64 bf16
  __shared__ unsigned short Ws[2][4096];  //  64 x 64 bf16
  const int tid = threadIdx.x;
  const int wave = tid >> 6, lane = tid & 63;
  const int col16 = lane & 15, g = lane >> 4;
  const int arow = blockIdx.y * 128, wrow = blockIdx.x * 64;
  const int wm = (wave >> 1) * 64, wn = (wave & 1) * 32;

  const unsigned short* gA[4];
  const unsigned short* gW[2];
  int dA[4], dW[2];
#pragma unroll
  for (int i = 0; i < 4; ++i) {
    const int c = i * 256 + tid;
    const int r = c >> 3, sl = c & 7;
    gA[i] = A + (size_t)(arow + r) * K + (sl ^ (r & 7)) * 8;
    dA[i] = c * 8;
  }
#pragma unroll
  for (int i = 0; i < 2; ++i) {
    const int c = i * 256 + tid;
    const int r = c >> 3, sl = c & 7;
    gW[i] = W + (size_t)(wrow + r) * K + (sl ^ (r & 7)) * 8;
    dW[i] = c * 8;
  }

  f32x4 acc[4][2];
#pragma unroll
  for (int i = 0; i < 4; ++i)
#pragma unroll
    for (int j = 0; j < 2; ++j) acc[i][j] = (f32x4){0.f, 0.f, 0.f, 0.f};

#pragma unroll
  for (int i = 0; i < 4; ++i) gload_lds16(gA[i], &As[0][dA[i]]);
#pragma unroll
  for (int i = 0; i < 2; ++i) gload_lds16(gW[i], &Ws[0][dW[i]]);

  int cur = 0;
  for (int k0 = 0; k0 < K; k0 += 64) {
    __syncthreads();
    if (k0 + 64 < K) {
      const int b = cur ^ 1, kk = k0 + 64;
#pragma unroll
      for (int i = 0; i < 4; ++i) gload_lds16(gA[i] + kk, &As[b][dA[i]]);
#pragma unroll
      for (int i = 0; i < 2; ++i) gload_lds16(gW[i] + kk, &Ws[b][dW[i]]);
    }
#pragma unroll
    for (int kh = 0; kh < 2; ++kh) {
      bf16x8 af[4], bfr[2];
#pragma unroll
      for (int i = 0; i < 4; ++i) {
        const int row = wm + i * 16 + col16;
        af[i] = *(const bf16x8*)(&As[cur][row * 64 + (((kh * 4 + g) ^ (row & 7)) * 8)]);
      }
#pragma unroll
      for (int j = 0; j < 2; ++j) {
        const int row = wn + j * 16 + col16;
        bfr[j] = *(const bf16x8*)(&Ws[cur][row * 64 + (((kh * 4 + g) ^ (row & 7)) * 8)]);
      }
#pragma unroll
      for (int i = 0; i < 4; ++i)
#pragma unroll
        for (int j = 0; j < 2; ++j)
          acc[i][j] = __builtin_amdgcn_mfma_f32_16x16x32_bf16(af[i], bfr[j], acc[i][j], 0, 0, 0);
    }
    cur ^= 1;
  }

#pragma unroll
  for (int i = 0; i < 4; ++i)
#pragma unroll
    for (int j = 0; j < 2; ++j) {
      const int col = wrow + wn + j * 16 + col16;
      const int row0 = arow + wm + i * 16 + g * 4;
#pragma unroll
      for (int r = 0; r < 4; ++r) {
        if constexpr (MODE == 0)
          ((float*)Cv)[(size_t)(row0 + r) * N + col] = acc[i][j][r];
        else
          ((unsigned short*)Cv)[(size_t)(row0 + r) * N + col] = f2u(acc[i][j][r]);
      }
    }
}

// ---------------------------------------------------------------------------
// Merged q_b + kv_b GEMM (one launch, 1792 blocks). bid<768: q_b; else kv_b
// (k_nope -> Kb; values -> Vt with PV permutation fused).
// ---------------------------------------------------------------------------
__global__ __launch_bounds__(256) void gemm_qkv(const unsigned short* __restrict__ qan,
                                                const unsigned short* __restrict__ wq,
                                                unsigned short* __restrict__ qbuf,
                                                const unsigned short* __restrict__ ckvn,
                                                const unsigned short* __restrict__ wkv,
                                                unsigned short* __restrict__ Kb,
                                                unsigned short* __restrict__ Vt) {
  __shared__ unsigned short As[2][8192];
  __shared__ unsigned short Ws[2][4096];
  const int tid = threadIdx.x;
  const int wave = tid >> 6, lane = tid & 63;
  const int col16 = lane & 15, g = lane >> 4;
  const int bid = (int)blockIdx.x;
  const bool isQ = bid < 768;
  int bx, by;
  if (isQ) { bx = bid % 48; by = bid / 48; }
  else { const int r = bid - 768; bx = r & 63; by = r >> 6; }
  const int K = isQ ? Q_LORA : KV_LORA;
  const unsigned short* A = isQ ? qan : ckvn;
  const unsigned short* W = isQ ? wq : wkv;
  const int arow = by * 128, wrow = bx * 64;
  const int wm = (wave >> 1) * 64, wn = (wave & 1) * 32;

  const unsigned short* gA[4];
  const unsigned short* gW[2];
  int dA[4], dW[2];
#pragma unroll
  for (int i = 0; i < 4; ++i) {
    const int c = i * 256 + tid;
    const int r = c >> 3, sl = c & 7;
    gA[i] = A + (size_t)(arow + r) * K + (sl ^ (r & 7)) * 8;
    dA[i] = c * 8;
  }
#pragma unroll
  for (int i = 0; i < 2; ++i) {
    const int c = i * 256 + tid;
    const int r = c >> 3, sl = c & 7;
    gW[i] = W + (size_t)(wrow + r) * K + (sl ^ (r & 7)) * 8;
    dW[i] = c * 8;
  }

  f32x4 acc[4][2];
#pragma unroll
  for (int i = 0; i < 4; ++i)
#pragma unroll
    for (int j = 0; j < 2; ++j) acc[i][j] = (f32x4){0.f, 0.f, 0.f, 0.f};

#pragma unroll
  for (int i = 0; i < 4; ++i) gload_lds16(gA[i], &As[0][dA[i]]);
#pragma unroll
  for (int i = 0; i < 2; ++i) gload_lds16(gW[i], &Ws[0][dW[i]]);

  int cur = 0;
  for (int k0 = 0; k0 < K; k0 += 64) {
    __syncthreads();
    if (k0 + 64 < K) {
      const int b = cur ^ 1, kk = k0 + 64;
#pragma unroll
      for (int i = 0; i < 4; ++i) gload_lds16(gA[i] + kk, &As[b][dA[i]]);
#pragma unroll
      for (int i = 0; i < 2; ++i) gload_lds16(gW[i] + kk, &Ws[b][dW[i]]);
    }
#pragma unroll
    for (int kh = 0; kh < 2; ++kh) {
      bf16x8 af[4], bfr[2];
#pragma unroll
      for (int i = 0; i < 4; ++i) {
        const int row = wm + i * 16 + col16;
        af[i] = *(const bf16x8*)(&As[cur][row * 64 + (((kh * 4 + g) ^ (row & 7)) * 8)]);
      }
#pragma unroll
      for (int j = 0; j < 2; ++j) {
        const int row = wn + j * 16 + col16;
        bfr[j] = *(const bf16x8*)(&Ws[cur][row * 64 + (((kh * 4 + g) ^ (row & 7)) * 8)]);
      }
#pragma unroll
      for (int i = 0; i < 4; ++i)
#pragma unroll
        for (int j = 0; j < 2; ++j)
          acc[i][j] = __builtin_amdgcn_mfma_f32_16x16x32_bf16(af[i], bfr[j], acc[i][j], 0, 0, 0);
    }
    cur ^= 1;
  }

#pragma unroll
  for (int i = 0; i < 4; ++i)
#pragma unroll
    for (int j = 0; j < 2; ++j) {
      const int col = wrow + wn + j * 16 + col16;
      const int row0 = arow + wm + i * 16 + g * 4;
      if (isQ) {
#pragma unroll
        for (int r = 0; r < 4; ++r)
          qbuf[(size_t)(row0 + r) * (N_HEADS * QHD) + col] = f2u(acc[i][j][r]);
      } else {
        const int hh = col >> 8, d = col & 255;
        if (d < NOPE) {
#pragma unroll
          for (int r = 0; r < 4; ++r)
            Kb[((size_t)hh * S_LEN + row0 + r) * QHD + d] = f2u(acc[i][j][r]);
        } else {
          // fused build_vt: Vt(h, d-128, (row0&~31) + perm(row0&31) + r)
          const int dv = d - NOPE;
          const int p0 = ((row0 & 15) >> 2) * 8 + ((row0 >> 4) & 1) * 4;
          u16x4 w4;
#pragma unroll
          for (int r = 0; r < 4; ++r) w4[r] = f2u(acc[i][j][r]);
          *(uint2*)(Vt + ((size_t)hh * VD + dv) * S_LEN + (row0 & ~31) + p0) =
              __builtin_bit_cast(uint2, w4);
        }
      }
    }
}

// ---------------------------------------------------------------------------
// Fused RMSNorm, bf16 input (ac bf16, ld 2112) -> bf16 out, vectorized x8.
// blockIdx.y = 0 -> q_a slice (1536), 1 -> kv slice (512).
// ---------------------------------------------------------------------------
__global__ __launch_bounds__(256) void rmsnorm2_kernel(const unsigned short* __restrict__ ac,
                                                       const float* __restrict__ wq,
                                                       const float* __restrict__ wkv,
                                                       unsigned short* __restrict__ qan,
                                                       unsigned short* __restrict__ ckvn) {
  const int row = blockIdx.x;
  const bool kv = blockIdx.y != 0;
  const unsigned short* x = ac + (size_t)row * AC_W + (kv ? Q_LORA : 0);
  const float* w = kv ? wkv : wq;
  unsigned short* dst = kv ? (ckvn + (size_t)row * KV_LORA) : (qan + (size_t)row * Q_LORA);
  const int dim = kv ? KV_LORA : Q_LORA;
  float ss = 0.f;
  for (int i0 = threadIdx.x * 8; i0 < dim; i0 += 2048) {
    const bf16x8 v = *(const bf16x8*)(x + i0);
#pragma unroll
    for (int e = 0; e < 8; ++e) {
      const float f = u2f((unsigned short)v[e]);
      ss += f * f;
    }
  }
#pragma unroll
  for (int off = 32; off; off >>= 1) ss += __shfl_xor(ss, off);
  __shared__ float red[4];
  const int wv = threadIdx.x >> 6, ln = threadIdx.x & 63;
  if (ln == 0) red[wv] = ss;
  __syncthreads();
  const float tot = red[0] + red[1] + red[2] + red[3];
  const float scale = rsqrtf(tot / (float)dim + 1e-6f);
  for (int i0 = threadIdx.x * 8; i0 < dim; i0 += 2048) {
    const bf16x8 v = *(const bf16x8*)(x + i0);
    u16x4 o0, o1;
#pragma unroll
    for (int e = 0; e < 4; ++e) {
      o0[e] = f2u(w[i0 + e] * (u2f((unsigned short)v[e]) * scale));
      o1[e] = f2u(w[i0 + 4 + e] * (u2f((unsigned short)v[4 + e]) * scale));
    }
    *(uint2*)(dst + i0) = __builtin_bit_cast(uint2, o0);
    *(uint2*)(dst + i0 + 4) = __builtin_bit_cast(uint2, o1);
  }
}

// ---------------------------------------------------------------------------
// RoPE, wave-parallel: 256 threads = 8 rows (one per 32-lane group), no
// barriers needed (in-wave lockstep orders loads before stores).
// ---------------------------------------------------------------------------
__global__ __launch_bounds__(256) void rope_kernel(unsigned short* __restrict__ q,
                                                   const unsigned short* __restrict__ ac,
                                                   unsigned short* __restrict__ Kb,
                                                   const int* __restrict__ pos_ids) {
  const int s = blockIdx.x * 8 + (threadIdx.x >> 5);
  const int j = threadIdx.x & 31;
  const float t = (float)pos_ids[s];
  const float invf = powf(50000.0f, -(float)(2 * j) / 64.0f);
  const float ang = t * invf;
  const float c = cosf(ang), sn = sinf(ang);
#pragma unroll
  for (int h = 0; h < N_HEADS; ++h) {
    unsigned short* base = q + (size_t)s * (N_HEADS * QHD) + h * QHD + NOPE;
    const float x0 = u2f(base[2 * j]), x1 = u2f(base[2 * j + 1]);
    base[j] = f2u(x0 * c - x1 * sn);
    base[32 + j] = f2u(x1 * c + x0 * sn);
  }
  const unsigned short* kb = ac + (size_t)s * AC_W + 2048;
  const float kb0 = u2f(kb[2 * j]), kb1 = u2f(kb[2 * j + 1]);
  const unsigned short r0 = f2u(kb0 * c - kb1 * sn);
  const unsigned short r1 = f2u(kb1 * c + kb0 * sn);
#pragma unroll
  for (int h = 0; h < N_HEADS; ++h) {
    unsigned short* kd = Kb + ((size_t)h * S_LEN + s) * QHD + NOPE;
    kd[j] = r0;
    kd[32 + j] = r1;
  }
}

// ---------------------------------------------------------------------------
// Split-2 MFMA flash attention (R9 structure; bf16 partials; conflict-free
// K and V LDS swizzles). Unchanged from round 15.
// ---------------------------------------------------------------------------
__global__ __launch_bounds__(256, 4) void flash_attn(const unsigned short* __restrict__ Q,   // (S,3072) pre-scaled
                                                     const unsigned short* __restrict__ Kb,  // (H,S,192)
                                                     const unsigned short* __restrict__ Vt,  // (H,128,S) permuted
                                                     unsigned short* __restrict__ Pb,        // (S,2,16,128) bf16
                                                     float2* __restrict__ mlb) {             // (S,2,16) {m,l}
  __shared__ unsigned short Ks[2][32 * QHD];   // 2 x 12 KB
  __shared__ unsigned short Vs[2][VD * 32];    // 2 x  8 KB
  const int tid = threadIdx.x;
  const int wave = tid >> 6, lane = tid & 63;
  const int g = lane >> 4, col = lane & 15;
  const int lin = (int)blockIdx.x;                    // 0..1023
  const int h = ((lin & 7) << 1) | ((lin >> 3) & 1);  // XCD owns a head pair
  const int s = (lin >> 4) & 1;                       // k-split
  const int z = lin >> 5;                             // 0..31
  int t;                                              // balanced qblock mapping
  if (z < 8) t = 31 - z;
  else if (z < 16) t = z - 8;
  else if (z < 24) t = 39 - z;
  else t = z - 16;
  const int qw = t * 64 + wave * 16;
  const int qr = qw + col;

  bf16x8 qf[6];
  {
    const unsigned short* qrow = Q + (size_t)qr * (N_HEADS * QHD) + h * QHD + g * 8;
#pragma unroll
    for (int i = 0; i < 6; ++i) qf[i] = *(const bf16x8*)(qrow + i * 32);
  }

  const unsigned short* KbH = Kb + (size_t)h * S_LEN * QHD;
  const unsigned short* VtH = Vt + (size_t)h * VD * S_LEN;

  // staging source offsets (pre-swizzled slots; fixed across tiles)
  int eK[3], eV[2];
#pragma unroll
  for (int i = 0; i < 3; ++i) {                 // 768 K chunks of 16B
    const int c = i * 256 + tid;
    const int r = c / 24, sl = c - r * 24;
    eK[i] = r * QHD + (((sl & 24) | ((sl & 7) ^ (r & 7)))) * 8;
  }
#pragma unroll
  for (int i = 0; i < 2; ++i) {                 // 512 V chunks of 16B
    const int L = i * 256 + tid;                // LDS linear chunk
    const int r = L >> 3, p = L & 7;
    const int px = p ^ (r & 7);
    const int d = 2 * r + (px >> 2), sl = px & 3;
    eV[i] = d * S_LEN + sl * 8;
  }

  f32x4 o[8];
#pragma unroll
  for (int i = 0; i < 8; ++i) o[i] = (f32x4){0.f, 0.f, 0.f, 0.f};
  float m = -1e30f, l = 0.f;

  const int nT = t + 1;  // tiles j = 2*it + s

  // prologue: stage tile j=s into buffer 0
  {
    const unsigned short* kp = KbH + (size_t)s * 32 * QHD;
    const unsigned short* vp = VtH + s * 32;
#pragma unroll
    for (int i = 0; i < 3; ++i) gload_lds16(kp + eK[i], &Ks[0][(i * 256 + tid) * 8]);
#pragma unroll
    for (int i = 0; i < 2; ++i) gload_lds16(vp + eV[i], &Vs[0][(i * 256 + tid) * 8]);
  }

  int xK[6];
#pragma unroll
  for (int i = 0; i < 6; ++i) xK[i] = ((4 * i + g) ^ (col & 7)) * 8;
  const int rbK = col * QHD;
  // V read: lane needs (d = db*16+col, chunk g): elem = db*512 + vlane
  const int vlane = (col >> 1) * 64 + ((((col & 1) << 2) + g) ^ (col >> 1)) * 8;

  for (int it = 0; it < nT; ++it) {
    __syncthreads();
    if (it + 1 < nT) {
      const int jn = 2 * (it + 1) + s;
      const unsigned short* kp = KbH + (size_t)jn * 32 * QHD;
      const unsigned short* vp = VtH + jn * 32;
      const int b = (it + 1) & 1;
#pragma unroll
      for (int i = 0; i < 3; ++i) gload_lds16(kp + eK[i], &Ks[b][(i * 256 + tid) * 8]);
#pragma unroll
      for (int i = 0; i < 2; ++i) gload_lds16(vp + eV[i], &Vs[b][(i * 256 + tid) * 8]);
    }
    const int k0 = 32 * (2 * it + s);
    if (k0 <= qw + 15) {
      const unsigned short* Ksc = Ks[it & 1];
      const unsigned short* Vsc = Vs[it & 1];

      f32x4 c0 = (f32x4){0.f, 0.f, 0.f, 0.f}, c1 = (f32x4){0.f, 0.f, 0.f, 0.f};
      __builtin_amdgcn_s_setprio(1);
#pragma unroll
      for (int dt = 0; dt < 6; ++dt) {
        const bf16x8 a0 = *(const bf16x8*)(Ksc + rbK + xK[dt]);
        const bf16x8 a1 = *(const bf16x8*)(Ksc + rbK + 16 * QHD + xK[dt]);
        c0 = __builtin_amdgcn_mfma_f32_16x16x32_bf16(a0, qf[dt], c0, 0, 0, 0);
        c1 = __builtin_amdgcn_mfma_f32_16x16x32_bf16(a1, qf[dt], c1, 0, 0, 0);
      }
      __builtin_amdgcn_s_setprio(0);

      // causal mask only on diagonal tiles (k = k0 + 16*frag + 4g + r)
      if (k0 + 31 > qw) {
#pragma unroll
        for (int r = 0; r < 4; ++r) {
          const int kk = k0 + 4 * g + r;
          if (kk > qr) c0[r] = -1e30f;
          if (kk + 16 > qr) c1[r] = -1e30f;
        }
      }
      float bm = fmaxf(fmaxf(fmaxf(c0[0], c0[1]), fmaxf(c0[2], c0[3])),
                       fmaxf(fmaxf(c1[0], c1[1]), fmaxf(c1[2], c1[3])));
      bm = fmaxf(bm, __shfl_xor(bm, 16));
      bm = fmaxf(bm, __shfl_xor(bm, 32));
      const bool skip = __all(bm <= m + 8.f);   // defer-max: p bounded by 2^8
      const float mn = skip ? m : fmaxf(m, bm);
      float ps = 0.f;
      bf16x8 pb;
#pragma unroll
      for (int r = 0; r < 4; ++r) {
        const float p0 = exp2f(c0[r] - mn);
        const float p1 = exp2f(c1[r] - mn);
        ps += p0 + p1;
        pb[r] = (short)f2u_fast(p0);
        pb[4 + r] = (short)f2u_fast(p1);
      }
      ps += __shfl_xor(ps, 16);
      ps += __shfl_xor(ps, 32);
      if (skip) {
        l += ps;
      } else {
        const float corr = exp2f(m - mn);
        l = l * corr + ps;
        m = mn;
#pragma unroll
        for (int i = 0; i < 8; ++i) {
          o[i][0] *= corr; o[i][1] *= corr; o[i][2] *= corr; o[i][3] *= corr;
        }
      }
      __builtin_amdgcn_s_setprio(1);
#pragma unroll
      for (int db = 0; db < 8; ++db) {
        const bf16x8 va = *(const bf16x8*)(Vsc + db * 512 + vlane);
        o[db] = __builtin_amdgcn_mfma_f32_16x16x32_bf16(va, pb, o[db], 0, 0, 0);
      }
      __builtin_amdgcn_s_setprio(0);
    }
  }

  // epilogue: bf16 unnormalized partials + (m,l)
  unsigned short* pr = Pb + (((size_t)qr * 2 + s) * N_HEADS + h) * VD;
#pragma unroll
  for (int db = 0; db < 8; ++db) {
    u16x4 w4;
#pragma unroll
    for (int r = 0; r < 4; ++r) w4[r] = f2u(o[db][r]);
    *(uint2*)(pr + db * 16 + 4 * g) = __builtin_bit_cast(uint2, w4);
  }
  if (g == 0) mlb[((size_t)qr * 2 + s) * N_HEADS + h] = make_float2(m, l);
}

// ---------------------------------------------------------------------------
// Merge the two k-splits + convert o_w to bf16 (both memory-bound, 1 launch).
// ---------------------------------------------------------------------------
__global__ __launch_bounds__(256) void combine2(const unsigned short* __restrict__ Pb,
                                                const float2* __restrict__ mlb,
                                                unsigned short* __restrict__ outb,
                                                const float* __restrict__ ow,
                                                unsigned short* __restrict__ owb) {
  const int nC = S_LEN * N_HEADS * VD / 8;           // 524288 combine items
  const int nT = nC + (D_MODEL * N_HEADS * VD) / 4;  // + 1048576 conv items
  for (int idx = blockIdx.x * 256 + threadIdx.x; idx < nT; idx += gridDim.x * 256) {
    if (idx < nC) {
      const int d8 = idx & 15, hq = idx >> 4;
      const int h = hq & 15, q = hq >> 4;
      const float2 a = mlb[((size_t)q * 2 + 0) * N_HEADS + h];
      const float2 b = mlb[((size_t)q * 2 + 1) * N_HEADS + h];
      const float M = fmaxf(a.x, b.x);
      float wA = exp2f(a.x - M), wB = exp2f(b.x - M);
      const float inv = 1.f / (wA * a.y + wB * b.y);
      wA *= inv; wB *= inv;
      const bf16x8 v0 = *(const bf16x8*)(Pb + (((size_t)q * 2 + 0) * N_HEADS + h) * VD + d8 * 8);
      const bf16x8 v1 = *(const bf16x8*)(Pb + (((size_t)q * 2 + 1) * N_HEADS + h) * VD + d8 * 8);
      u16x4 o0, o1;
#pragma unroll
      for (int e = 0; e < 4; ++e) {
        o0[e] = f2u(u2f((unsigned short)v0[e]) * wA + u2f((unsigned short)v1[e]) * wB);
        o1[e] = f2u(u2f((unsigned short)v0[4 + e]) * wA + u2f((unsigned short)v1[4 + e]) * wB);
      }
      unsigned short* dst = outb + ((size_t)q * N_HEADS + h) * VD + d8 * 8;
      *(uint2*)(dst) = __builtin_bit_cast(uint2, o0);
      *(uint2*)(dst + 4) = __builtin_bit_cast(uint2, o1);
    } else {
      const int i = idx - nC;
      const float4 v = ((const float4*)ow)[i];
      u16x4 u;
      u[0] = f2u(v.x); u[1] = f2u(v.y); u[2] = f2u(v.z); u[3] = f2u(v.w);
      ((u16x4*)owb)[i] = u;
    }
  }
}

// ---------------------------------------------------------------------------
extern "C" void kernel_launch(void* const* d_in, const int* in_sizes, int n_in,
                              void* d_out, int out_size, void* d_ws, size_t ws_size,
                              hipStream_t stream) {
  const float* hidden    = (const float*)d_in[0];
  const int*   pos       = (const int*)d_in[1];
  const float* q_a_w     = (const float*)d_in[2];
  const float* q_a_ln_w  = (const float*)d_in[3];
  const float* q_b_w     = (const float*)d_in[4];
  const float* kv_a_w    = (const float*)d_in[5];
  const float* kv_a_ln_w = (const float*)d_in[6];
  const float* kv_b_w    = (const float*)d_in[7];
  const float* o_w       = (const float*)d_in[8];
  float* out = (float*)d_out;
  (void)in_sizes; (void)n_in; (void)out_size; (void)ws_size;

  // workspace layout (bytes); total ~94 MB
  char* base = (char*)d_ws;
  unsigned short* qbuf  = (unsigned short*)(base);              // S*3072 bf16  12.58MB
  unsigned short* Pbuf  = (unsigned short*)(base + 12582912);   // S*2*16*128 bf16 = 16.78MB
  unsigned short* qbwb  = (unsigned short*)(base + 12582912);   //   overlay: q_b bf16 9.44MB (dead before flash)
  unsigned short* acb   = (unsigned short*)(base + 29360128);   // S*2112 bf16   8.65MB
  unsigned short* qan   = (unsigned short*)(base + 46661632);   // S*1536 bf16   6.29MB
  float2*         mlb   = (float2*)(base + 46661632);           //   overlay: S*2*16 float2 (qan dead by flash)
  unsigned short* ckvn  = (unsigned short*)(base + 52953088);   // S*512 bf16    2.10MB
  unsigned short* Hb    = (unsigned short*)(base + 55050240);   // S*2048 bf16   8.39MB
  unsigned short* Vt    = (unsigned short*)(base + 55050240);   //   overlay (Hb dead after a-proj)
  unsigned short* wbuf  = (unsigned short*)(base + 63438848);   // a-weights bf16 8.65MB; later o_w bf16
  unsigned short* attnb = (unsigned short*)(base + 72876032);   // S*2048 bf16   8.39MB
  unsigned short* kvbwb = (unsigned short*)(base + 72876032);   //   overlay: kv_b bf16 4.19MB (dead before combine2)
  unsigned short* Kb    = (unsigned short*)(base + 81264640);   // 16*S*192 bf16 12.58MB

  const dim3 b256(256);
  // 192^-0.5 * log2(e): scores come out of QK^T directly in log2 domain
  const float qscale = 0.07216878364870323f * 1.4426950408889634f;

  // ALL input conversions in one launch
  conv_all<<<2048, b256, 0, stream>>>(hidden, q_a_w, kv_a_w, q_b_w, kv_b_w,
                                      Hb, wbuf, qbwb, kvbwb, qscale);

  // fused a-proj: C = acb bf16 (S x 2112)
  gemm_mfma<1><<<dim3(AC_W / 64, S_LEN / 128), b256, 0, stream>>>(Hb, wbuf, acb, AC_W, D_MODEL);

  // fused double rmsnorm (q_a and kv slices), bf16 in
  rmsnorm2_kernel<<<dim3(S_LEN, 2), b256, 0, stream>>>(acb, q_a_ln_w, kv_a_ln_w, qan, ckvn);

  // merged q_b + kv_b GEMMs (one launch, 1792 blocks)
  gemm_qkv<<<dim3(1792), b256, 0, stream>>>(qan, qbwb, qbuf, ckvn, kvbwb, Kb, Vt);

  // rope: qbuf q_pe in place; k_pe (bf16) -> Kb cols 128..192 (all heads)
  rope_kernel<<<S_LEN / 8, b256, 0, stream>>>(qbuf, acb, Kb, pos);

  // split-2 flash (bf16 partials -> Pbuf, overwrites dead qbwb; ml over qan)
  flash_attn<<<dim3(1024), b256, 0, stream>>>(qbuf, Kb, Vt, Pbuf, mlb);

  // combine splits + convert o_w -> wbuf (free after a-proj)
  combine2<<<2048, b256, 0, stream>>>(Pbuf, mlb, attnb, o_w, wbuf);

  // out = attnb @ o_w^T
  gemm_mfma<0><<<dim3(D_MODEL / 64, S_LEN / 128), b256, 0, stream>>>(attnb, wbuf, out, D_MODEL, N_HEADS * VD);
}